// Round 18
// baseline (219.106 us; speedup 1.0000x reference)
//
#include <hip/hip_runtime.h>
#include <math.h>
#include <float.h>
#include <limits.h>

// ---------------- problem constants (fixed by setup_inputs) ----------------
#define HH 1024
#define WW 1024
#define NPIX (HH*WW)          // 1048576
#define RH 1449               // ceil(1024*sqrt(2))
#define RW 1449
#define NBSEG 5000
#define START 211             // int((rot_bbox_w - 1024)/2) for 45 deg

// k_mm tiling: 64x8 px/block, 2 px/thread, halo 3
#define TW 64
#define TH 8
#define HALO 3
#define TSX (TW + 2*HALO)     // 70
#define TSY (TH + 2*HALO)     // 14
#define TST 71                // padded LDS row stride
#define NBLK_MM 2048          // (1024/64) x (1024/8)

// output layout (floats, concatenated in return order)
#define OUT_XYWH_OFF  0          // 5000*4
#define OUT_SIZE_OFF  20000      // 5000
#define OUT_COLOR_OFF 25000      // 5000*3*25
#define OUT_TEX_OFF   400000     // 5000*3*8*10
#define OUT_TOTAL     1600000

__device__ __forceinline__ unsigned bf16t(float v) { return __float_as_uint(v) >> 16; }
__device__ __forceinline__ float bf16f(unsigned h) { return __uint_as_float(h << 16); }

// ---------------- kernels ----------------

// Pass 1, 2D-tiled, 2 px/thread: zero-padded 70x14x3 img tile in LDS (11.9 KB);
// stencil + rot taps all LDS; butterfly/barrier/tile-load amortized over 2 px
// (r17 lesson: 1 px/thread made the 144-op minmax butterfly per-pixel).
__global__ __launch_bounds__(256, 6) void k_mm(const float* __restrict__ img,
                                               const int* __restrict__ reg,
                                               int* __restrict__ cnt,
                                               int* __restrict__ rank,
                                               uint2* __restrict__ grad2,
                                               unsigned short* __restrict__ cpq,
                                               float* __restrict__ pmin,
                                               float* __restrict__ pmax,
                                               float cb, float sb, float cf, float sf) {
  __shared__ float tile[3][TSY * TST];
  int tid = threadIdx.x;
  int x0 = blockIdx.x * TW, y0 = blockIdx.y * TH;

  // coalesced zero-padded tile load (rows of 70; lanes consecutive)
  for (int i = tid; i < 3 * TSY * TSX; i += 256) {
    int c = i / (TSY * TSX); int r = i - c * (TSY * TSX);
    int ly = r / TSX, lx = r - ly * TSX;
    int gx = x0 - HALO + lx, gy = y0 - HALO + ly;
    float v = ((unsigned)gx < (unsigned)WW && (unsigned)gy < (unsigned)HH)
              ? img[(long)c * NPIX + (long)gy * WW + gx] : 0.0f;
    tile[c][ly * TST + lx] = v;
  }
  __syncthreads();

  int tx = tid & 63, ty = tid >> 6;
  int x = x0 + tx;

  float vmn[12], vmx[12];
  #pragma unroll
  for (int m = 0; m < 12; ++m) { vmn[m] = FLT_MAX; vmx[m] = -FLT_MAX; }

  #pragma unroll
  for (int k = 0; k < 2; ++k) {
    int yt = ty + 4 * k;            // tile-local row 0..7
    int y = y0 + yt;
    int p = y * WW + x;
    int s = reg[p];
    if ((unsigned)s < (unsigned)NBSEG) rank[p] = atomicAdd(&cnt[s], 1);

    // ---- back-map center (exact expressions, as all passing rounds)
    float sx, sy;
    {
      #pragma clang fp contract(off)
      float dx = (float)(x + START) - 1024.5f;   // ncx of 2050-grid
      float dy = (float)(y + START) - 1024.5f;
      sx = cb*dx - sb*dy + 724.0f;               // cx of 1449-grid
      sy = sb*dx + cb*dy + 724.0f;
    }
    bool valid2 = (sx >= -0.5f) && (sx <= (float)RW - 0.5f) &&
                  (sy >= -0.5f) && (sy <= (float)RH - 0.5f);
    int ix = min(max((int)rintf(sx), 0), RW - 1);
    int iy = min(max((int)rintf(sy), 0), RH - 1);

    float fxc, fyc;
    {
      #pragma clang fp contract(off)
      float ddx = (float)ix - 724.0f;
      float ddy = (float)iy - 724.0f;
      fxc = cf*ddx - sf*ddy + 511.5f;
      fyc = sf*ddx + cf*ddy + 511.5f;
    }

    int lofs[9];              // LDS-local tap offsets (valid when okm bit set)
    unsigned okm = 0;
    #pragma unroll
    for (int t = 0; t < 9; ++t) {
      const int dxi = (t % 3) - 1, dyi = (t / 3) - 1;
      int rx = ix + dxi, ry = iy + dyi;
      bool inside = ((unsigned)rx < (unsigned)RW) && ((unsigned)ry < (unsigned)RH);
      float fx = fxc + (cf*(float)dxi - sf*(float)dyi);   // scalar-folded constants
      float fy = fyc + (sf*(float)dxi + cf*(float)dyi);
      bool v1 = (fx >= -0.5f) && (fx <= 1023.5f) && (fy >= -0.5f) && (fy <= 1023.5f);
      int jx = min(max((int)rintf(fx), 0), WW - 1);
      int jy = min(max((int)rintf(fy), 0), HH - 1);
      // unmasked taps satisfy |jx-x|<=2, |jy-y|<=2 -> inside tile; clamp for masked
      int lx = min(max(jx - x0 + HALO, 0), TSX - 1);
      int ly = min(max(jy - y0 + HALO, 0), TSY - 1);
      lofs[t] = ly * TST + lx;
      okm |= ((unsigned)(inside && v1)) << t;
    }

    int cbase = (yt + HALO) * TST + (tx + HALO);
    unsigned qc[3];
    #pragma unroll
    for (int c = 0; c < 3; ++c) {
      const float* t = &tile[c][0];
      float n00 = t[cbase - TST - 1], n01 = t[cbase - TST], n02 = t[cbase - TST + 1];
      float n10 = t[cbase - 1],       ctr = t[cbase],       n12 = t[cbase + 1];
      float n20 = t[cbase + TST - 1], n21 = t[cbase + TST], n22 = t[cbase + TST + 1];
      float a0 = -3.0f*n00 + 3.0f*n02 + 10.0f*n10 + 10.0f*n12 - 3.0f*n20 + 3.0f*n22;
      float a1 = -3.0f*n00 + 10.0f*n01 - 3.0f*n02 + 3.0f*n20 + 10.0f*n21 + 3.0f*n22;

      float m0 = (okm & 1u)   ? t[lofs[0]] : 0.0f;
      float m1 = (okm & 2u)   ? t[lofs[1]] : 0.0f;
      float m2 = (okm & 4u)   ? t[lofs[2]] : 0.0f;
      float m3 = (okm & 8u)   ? t[lofs[3]] : 0.0f;
      float m5 = (okm & 32u)  ? t[lofs[5]] : 0.0f;
      float m6 = (okm & 64u)  ? t[lofs[6]] : 0.0f;
      float m7 = (okm & 128u) ? t[lofs[7]] : 0.0f;
      float m8 = (okm & 256u) ? t[lofs[8]] : 0.0f;
      float r0 = -3.0f*m0 + 3.0f*m2 + 10.0f*m3 + 10.0f*m5 - 3.0f*m6 + 3.0f*m8;
      float r1 = -3.0f*m0 + 10.0f*m1 - 3.0f*m2 + 3.0f*m6 + 10.0f*m7 + 3.0f*m8;
      float b0 = valid2 ? r0 : 0.0f;
      float b1 = valid2 ? r1 : 0.0f;

      unsigned ua0 = bf16t(a0), ua1 = bf16t(a1), ub0 = bf16t(b0), ub1 = bf16t(b1);
      float a0r = bf16f(ua0), a1r = bf16f(ua1), b0r = bf16f(ub0), b1r = bf16f(ub1);

      grad2[(long)c * NPIX + p] = make_uint2(ua0 | (ua1 << 16), ub0 | (ub1 << 16));

      int cc = (int)(ctr * 24.0f);   // (img*(cb-1)).astype(int32)
      qc[c] = (unsigned)min(max(cc, 0), 24);

      vmn[2*c]     = fminf(vmn[2*c],     a0r); vmx[2*c]     = fmaxf(vmx[2*c],     a0r);
      vmn[2*c + 1] = fminf(vmn[2*c + 1], a1r); vmx[2*c + 1] = fmaxf(vmx[2*c + 1], a1r);
      vmn[6 + 2*c]     = fminf(vmn[6 + 2*c],     b0r); vmx[6 + 2*c]     = fmaxf(vmx[6 + 2*c],     b0r);
      vmn[6 + 2*c + 1] = fminf(vmn[6 + 2*c + 1], b1r); vmx[6 + 2*c + 1] = fmaxf(vmx[6 + 2*c + 1], b1r);
    }
    cpq[p] = (unsigned short)(qc[0] + 25u*qc[1] + 625u*qc[2]);   // < 15625, fits 14b
  }

  #pragma unroll
  for (int off = 32; off >= 1; off >>= 1) {
    #pragma unroll
    for (int m = 0; m < 12; ++m) {
      vmn[m] = fminf(vmn[m], __shfl_xor(vmn[m], off));
      vmx[m] = fmaxf(vmx[m], __shfl_xor(vmx[m], off));
    }
  }
  __shared__ float smn[12][4], smx[12][4];
  int wv = tid >> 6;
  if ((tid & 63) == 0) {
    #pragma unroll
    for (int m = 0; m < 12; ++m) { smn[m][wv] = vmn[m]; smx[m][wv] = vmx[m]; }
  }
  __syncthreads();
  if (tid < 12) {
    int m = tid;
    float mn = fminf(fminf(smn[m][0], smn[m][1]), fminf(smn[m][2], smn[m][3]));
    float mx = fmaxf(fmaxf(smx[m][0], smx[m][1]), fmaxf(smx[m][2], smx[m][3]));
    int fb = blockIdx.y * gridDim.x + blockIdx.x;
    pmin[m * NBLK_MM + fb] = mn;
    pmax[m * NBLK_MM + fb] = mx;
  }
}

// Fused: blocks 0..11 reduce one map's partials -> gmm; block 12 prefix-scans counts.
__global__ __launch_bounds__(1024) void k_redscan(const float* __restrict__ pmin,
                                                  const float* __restrict__ pmax,
                                                  const int* __restrict__ cnt,
                                                  float* __restrict__ gmm,
                                                  int* __restrict__ start) {
  int t = threadIdx.x;
  if (blockIdx.x < 12) {
    int m = blockIdx.x;
    float mn = fminf(pmin[m * NBLK_MM + t], pmin[m * NBLK_MM + 1024 + t]);
    float mx = fmaxf(pmax[m * NBLK_MM + t], pmax[m * NBLK_MM + 1024 + t]);
    #pragma unroll
    for (int off = 32; off >= 1; off >>= 1) {
      mn = fminf(mn, __shfl_xor(mn, off));
      mx = fmaxf(mx, __shfl_xor(mx, off));
    }
    __shared__ float smn[16], smx[16];
    int wv = t >> 6;
    if ((t & 63) == 0) { smn[wv] = mn; smx[wv] = mx; }
    __syncthreads();
    if (t == 0) {
      #pragma unroll
      for (int i = 1; i < 16; ++i) { mn = fminf(mn, smn[i]); mx = fmaxf(mx, smx[i]); }
      gmm[2*m] = mn; gmm[2*m + 1] = mx;
    }
    return;
  }
  // block 12: exclusive scan of 5000 counts
  __shared__ int part[1024];
  int base = t * 5;
  int v[5]; int sum = 0;
  #pragma unroll
  for (int j = 0; j < 5; ++j) {
    v[j] = (base + j < NBSEG) ? cnt[base + j] : 0;
    sum += v[j];
  }
  part[t] = sum;
  __syncthreads();
  #pragma unroll
  for (int d = 1; d < 1024; d <<= 1) {
    int xv = (t >= d) ? part[t - d] : 0;
    __syncthreads();
    part[t] += xv;
    __syncthreads();
  }
  int run = (t > 0) ? part[t - 1] : 0;   // exclusive
  #pragma unroll
  for (int j = 0; j < 5; ++j) {
    int i = base + j;
    if (i <= NBSEG) start[i] = run;
    run += v[j];
  }
}

// Pass 2: read bf16 grad planes + packed color bins COALESCED, quantize
// (mul form, params from gmm in-block), pack 16B record, atomic-free scatter.
__global__ __launch_bounds__(256) void k_bin(const int* __restrict__ reg,
                                             const int* __restrict__ rank,
                                             const int* __restrict__ start,
                                             const float* __restrict__ gmm,
                                             const uint2* __restrict__ grad2,
                                             const unsigned short* __restrict__ cpq,
                                             uint4* __restrict__ rec) {
  __shared__ float params[48];
  if (threadIdx.x < 24) {
    int t = threadIdx.x;
    int c = t / 8, k = t % 8;
    int b = (k < 4) ? (2*c + (k & 1)) : (6 + 2*c + (k & 1));
    bool pos = ((k >> 1) & 1) == 0;   // k in {0,1,4,5} -> max(.,0); {2,3,6,7} -> min(.,0)
    float mn = gmm[2*b], mx = gmm[2*b + 1];
    float hmin, hmax;
    if (pos) { hmin = fmaxf(mn, 0.0f); hmax = fmaxf(mx, 0.0f); }
    else     { hmin = fminf(mn, 0.0f); hmax = fminf(mx, 0.0f); }
    params[2*t]     = hmin;
    params[2*t + 1] = 9.0f / (hmax - hmin);   // mul instead of div
  }
  __syncthreads();

  int p = blockIdx.x * 256 + threadIdx.x;
  int s = reg[p];
  if ((unsigned)s >= (unsigned)NBSEG) return;

  unsigned q[24];
  #pragma unroll
  for (int c = 0; c < 3; ++c) {
    uint2 g = grad2[(long)c * NPIX + p];
    float gv[2] = { bf16f(g.x & 0xFFFFu), __uint_as_float(g.x & 0xFFFF0000u) };
    float rv[2] = { bf16f(g.y & 0xFFFFu), __uint_as_float(g.y & 0xFFFF0000u) };
    #pragma unroll
    for (int d = 0; d < 2; ++d) {
      {
        int m = c*8 + d;
        float v = fmaxf(gv[d], 0.0f);
        int qq = (int)((v - params[2*m]) * params[2*m + 1]);
        q[m] = (unsigned)min(max(qq, 0), 9);
      }
      {
        int m = c*8 + 2 + d;
        float v = fminf(gv[d], 0.0f);
        int qq = (int)((v - params[2*m]) * params[2*m + 1]);
        q[m] = (unsigned)min(max(qq, 0), 9);
      }
      {
        int m = c*8 + 4 + d;
        float v = fmaxf(rv[d], 0.0f);
        int qq = (int)((v - params[2*m]) * params[2*m + 1]);
        q[m] = (unsigned)min(max(qq, 0), 9);
      }
      {
        int m = c*8 + 6 + d;
        float v = fminf(rv[d], 0.0f);
        int qq = (int)((v - params[2*m]) * params[2*m + 1]);
        q[m] = (unsigned)min(max(qq, 0), 9);
      }
    }
  }

  unsigned trip[8];
  #pragma unroll
  for (int j = 0; j < 8; ++j)
    trip[j] = q[3*j] + 10u*q[3*j + 1] + 100u*q[3*j + 2];
  unsigned cp = (unsigned)cpq[p];

  uint4 r;
  r.x = (unsigned)p | (trip[0] << 20);
  r.y = trip[1] | (trip[2] << 10) | (trip[3] << 20);
  r.z = trip[4] | (trip[5] << 10) | (trip[6] << 20);
  r.w = trip[7] | (cp << 10);

  rec[start[s] + rank[p]] = r;   // atomic-free scatter
}

// One block per segment: STREAM the 16B records coalesced, bfe-unpack,
// ballot+popcount per (map,bin), lane-sliced register accumulate,
// one flush of 5 LDS atomics per wave. Shuffle-reduced bbox from packed p.
__global__ __launch_bounds__(256) void k_accum(const uint4* __restrict__ rec,
                                               const int* __restrict__ start,
                                               float* __restrict__ out) {
  __shared__ unsigned hist[316];
  __shared__ int bb[4];
  int tid = threadIdx.x;
  int lane = tid & 63;

  for (int i = tid; i < 316; i += 256) hist[i] = 0;
  if (tid == 0) { bb[0] = INT_MAX; bb[1] = INT_MAX; bb[2] = INT_MIN; bb[3] = INT_MIN; }
  __syncthreads();

  int s = blockIdx.x;
  int beg = start[s], end = start[s + 1];
  int n = end - beg;

  unsigned acc[5] = {0, 0, 0, 0, 0};   // lane-sliced: acc[j] counts bin (64*j + lane)
  int xmn = INT_MAX, ymn = INT_MAX, xmx = INT_MIN, ymx = INT_MIN;

  for (int base2 = beg; base2 < end; base2 += 256) {
    int i = base2 + tid;
    bool act = i < end;
    uint4 r = rec[act ? i : beg];
    unsigned inv = act ? 0u : 0xFFu;   // OR-mask pushes bins out of range for pad lanes

    unsigned tr[8];
    tr[0] = r.x >> 20;
    tr[1] = r.y & 0x3FFu; tr[2] = (r.y >> 10) & 0x3FFu; tr[3] = r.y >> 20;
    tr[4] = r.z & 0x3FFu; tr[5] = (r.z >> 10) & 0x3FFu; tr[6] = r.z >> 20;
    tr[7] = r.w & 0x3FFu;
    unsigned cp = r.w >> 10;

    unsigned qv[24];
    #pragma unroll
    for (int j = 0; j < 8; ++j) {
      unsigned t = tr[j];
      unsigned q2 = t / 100u; unsigned rr = t - 100u*q2;
      unsigned q1 = rr / 10u; unsigned q0 = rr - 10u*q1;
      qv[3*j]     = q0 | inv;
      qv[3*j + 1] = q1 | inv;
      qv[3*j + 2] = q2 | inv;
    }
    unsigned c0 = (cp % 25u) | inv;
    unsigned rem = cp / 25u;
    unsigned c1 = (rem % 25u) | inv;
    unsigned c2 = (rem / 25u) | inv;

    if (act) {
      unsigned p = r.x & 0xFFFFFu;
      int x = (int)(p & 1023u), y = (int)(p >> 10);
      xmn = min(xmn, x); ymn = min(ymn, y);
      xmx = max(xmx, x); ymx = max(ymx, y);
    }

    #pragma unroll
    for (int m = 0; m < 24; ++m) {
      #pragma unroll
      for (int b = 0; b < 10; ++b) {
        unsigned cntb = (unsigned)__popcll(__ballot(qv[m] == (unsigned)b));
        int idx = m * 10 + b;
        acc[idx >> 6] += (lane == (idx & 63)) ? cntb : 0u;
      }
    }
    unsigned qcs[3] = { c0, c1, c2 };
    #pragma unroll
    for (int cm = 0; cm < 3; ++cm) {
      #pragma unroll
      for (int b = 0; b < 25; ++b) {
        unsigned cntb = (unsigned)__popcll(__ballot(qcs[cm] == (unsigned)b));
        int idx = 240 + cm * 25 + b;
        acc[idx >> 6] += (lane == (idx & 63)) ? cntb : 0u;
      }
    }
  }

  #pragma unroll
  for (int j = 0; j < 5; ++j) {
    int idx = j * 64 + lane;
    if (idx < 315 && acc[j]) atomicAdd(&hist[idx], acc[j]);
  }

  #pragma unroll
  for (int off = 32; off >= 1; off >>= 1) {
    xmn = min(xmn, __shfl_xor(xmn, off));
    ymn = min(ymn, __shfl_xor(ymn, off));
    xmx = max(xmx, __shfl_xor(xmx, off));
    ymx = max(ymx, __shfl_xor(ymx, off));
  }
  if (lane == 0) {
    atomicMin(&bb[0], xmn); atomicMin(&bb[1], ymn);
    atomicMax(&bb[2], xmx); atomicMax(&bb[3], ymx);
  }
  __syncthreads();

  if (tid == 0) {
    out[4*s + 0] = (float)bb[0];
    out[4*s + 1] = (float)bb[1];
    out[4*s + 2] = (float)(bb[2] - bb[0]);
    out[4*s + 3] = (float)(bb[3] - bb[1]);
    out[OUT_SIZE_OFF + s] = (float)n;
  }
  bool ok = n > 0;
  float cden = 3.0f * (float)n, tden = 24.0f * (float)n;
  for (int i = tid; i < 240; i += 256)
    out[OUT_TEX_OFF + s*240 + i] = ok ? (float)hist[i] / tden : 0.0f;
  for (int i = tid; i < 75; i += 256)
    out[OUT_COLOR_OFF + s*75 + i] = ok ? (float)hist[240 + i] / cden : 0.0f;
}

// ---------------- launch ----------------

extern "C" void kernel_launch(void* const* d_in, const int* in_sizes, int n_in,
                              void* d_out, int out_size, void* d_ws, size_t ws_size,
                              hipStream_t stream) {
  const float* img = (const float*)d_in[0];
  const int*   reg = (const int*)d_in[1];
  float* out = (float*)d_out;

  char* ws = (char*)d_ws;
  size_t off = 0;
  uint2*  grad2 = (uint2*)(ws + off);  off += (size_t)3 * NPIX * 8;   off = (off + 255) & ~(size_t)255;
  uint4*  rec   = (uint4*)(ws + off);  off += (size_t)(NPIX + 256) * 16; off = (off + 255) & ~(size_t)255;
  int*    rank  = (int*)(ws + off);    off += (size_t)NPIX * 4;       off = (off + 255) & ~(size_t)255;
  unsigned short* cpq = (unsigned short*)(ws + off); off += (size_t)NPIX * 2; off = (off + 255) & ~(size_t)255;
  int*    cnt   = (int*)(ws + off);    off += 5120 * 4;
  int*    start = (int*)(ws + off);    off += 5008 * 4;
  float*  gmm   = (float*)(ws + off);  off += 32 * 4;                 off = (off + 255) & ~(size_t)255;
  float*  pmin  = (float*)(ws + off);  off += (size_t)12 * NBLK_MM * 4;
  float*  pmax  = (float*)(ws + off);  off += (size_t)12 * NBLK_MM * 4;
  (void)ws_size; (void)in_sizes; (void)n_in; (void)out_size;

  double th  = 45.0 * (M_PI / 180.0);
  float cf = (float)cos(th),  sf = (float)sin(th);    // forward +45
  double thb = -45.0 * (M_PI / 180.0);
  float cbk = (float)cos(thb), sbk = (float)sin(thb); // backward -45

  dim3 gMM(WW / TW, HH / TH);   // 16 x 128 = 2048 blocks

  hipMemsetAsync(cnt, 0, 5120 * sizeof(int), stream);   // replaces k_zero dispatch
  k_mm     <<<gMM,       256,  0, stream>>>(img, reg, cnt, rank, grad2, cpq, pmin, pmax, cbk, sbk, cf, sf);
  k_redscan<<<13,        1024, 0, stream>>>(pmin, pmax, cnt, gmm, start);
  k_bin    <<<NPIX/256,  256,  0, stream>>>(reg, rank, start, gmm, grad2, cpq, rec);
  k_accum  <<<NBSEG,     256,  0, stream>>>(rec, start, out);
}

// Round 19
// 216.251 us; speedup vs baseline: 1.0132x; 1.0132x over previous
//
#include <hip/hip_runtime.h>
#include <math.h>
#include <float.h>
#include <limits.h>

// ---------------- problem constants (fixed by setup_inputs) ----------------
#define HH 1024
#define WW 1024
#define NPIX (HH*WW)          // 1048576
#define RH 1449               // ceil(1024*sqrt(2))
#define RW 1449
#define NBSEG 5000
#define START 211             // int((rot_bbox_w - 1024)/2) for 45 deg

// k_mm tiling (r17 config — best measured): 64x4 px/block, 1 px/thread, halo 3
#define TW 64
#define TH 4
#define HALO 3
#define TSX (TW + 2*HALO)     // 70
#define TSY (TH + 2*HALO)     // 10
#define TST 71                // padded LDS row stride
#define NBLK_MM 4096          // (1024/64) x (1024/4)

// output layout (floats, concatenated in return order)
#define OUT_XYWH_OFF  0          // 5000*4
#define OUT_SIZE_OFF  20000      // 5000
#define OUT_COLOR_OFF 25000      // 5000*3*25
#define OUT_TEX_OFF   400000     // 5000*3*8*10
#define OUT_TOTAL     1600000

__device__ __forceinline__ unsigned bf16t(float v) { return __float_as_uint(v) >> 16; }
__device__ __forceinline__ float bf16f(unsigned h) { return __uint_as_float(h << 16); }

// ---------------- kernels ----------------

// Pass 1 (r17 structure): zero-padded 70x10x3 img tile in LDS; stencil + rot
// taps all LDS. rank and color-bin packed into ONE int plane:
// rkcp[p] = (rank << 14) | cpq   (rank <= ~270 << 2^18; cpq < 15625 fits 14b).
__global__ __launch_bounds__(256, 6) void k_mm(const float* __restrict__ img,
                                               const int* __restrict__ reg,
                                               int* __restrict__ cnt,
                                               unsigned* __restrict__ rkcp,
                                               uint2* __restrict__ grad2,
                                               float* __restrict__ pmin,
                                               float* __restrict__ pmax,
                                               float cb, float sb, float cf, float sf) {
  __shared__ float tile[3][TSY * TST];
  int tid = threadIdx.x;
  int x0 = blockIdx.x * TW, y0 = blockIdx.y * TH;

  // coalesced zero-padded tile load (rows of 70; lanes consecutive)
  for (int i = tid; i < 3 * TSY * TSX; i += 256) {
    int c = i / (TSY * TSX); int r = i - c * (TSY * TSX);
    int ly = r / TSX, lx = r - ly * TSX;
    int gx = x0 - HALO + lx, gy = y0 - HALO + ly;
    float v = ((unsigned)gx < (unsigned)WW && (unsigned)gy < (unsigned)HH)
              ? img[(long)c * NPIX + (long)gy * WW + gx] : 0.0f;
    tile[c][ly * TST + lx] = v;
  }
  __syncthreads();

  int tx = tid & 63, ty = tid >> 6;
  int x = x0 + tx, y = y0 + ty;
  int p = y * WW + x;
  int s = reg[p];
  int rank = ((unsigned)s < (unsigned)NBSEG) ? atomicAdd(&cnt[s], 1) : 0;

  // ---- back-map center (exact expressions, as all passing rounds)
  float sx, sy;
  {
    #pragma clang fp contract(off)
    float dx = (float)(x + START) - 1024.5f;   // ncx of 2050-grid
    float dy = (float)(y + START) - 1024.5f;
    sx = cb*dx - sb*dy + 724.0f;               // cx of 1449-grid
    sy = sb*dx + cb*dy + 724.0f;
  }
  bool valid2 = (sx >= -0.5f) && (sx <= (float)RW - 0.5f) &&
                (sy >= -0.5f) && (sy <= (float)RH - 0.5f);
  int ix = min(max((int)rintf(sx), 0), RW - 1);
  int iy = min(max((int)rintf(sy), 0), RH - 1);

  float fxc, fyc;
  {
    #pragma clang fp contract(off)
    float ddx = (float)ix - 724.0f;
    float ddy = (float)iy - 724.0f;
    fxc = cf*ddx - sf*ddy + 511.5f;
    fyc = sf*ddx + cf*ddy + 511.5f;
  }

  int lofs[9];              // LDS-local tap offsets (valid when okm bit set)
  unsigned okm = 0;
  #pragma unroll
  for (int t = 0; t < 9; ++t) {
    const int dxi = (t % 3) - 1, dyi = (t / 3) - 1;
    int rx = ix + dxi, ry = iy + dyi;
    bool inside = ((unsigned)rx < (unsigned)RW) && ((unsigned)ry < (unsigned)RH);
    float fx = fxc + (cf*(float)dxi - sf*(float)dyi);   // scalar-folded constants
    float fy = fyc + (sf*(float)dxi + cf*(float)dyi);
    bool v1 = (fx >= -0.5f) && (fx <= 1023.5f) && (fy >= -0.5f) && (fy <= 1023.5f);
    int jx = min(max((int)rintf(fx), 0), WW - 1);
    int jy = min(max((int)rintf(fy), 0), HH - 1);
    // unmasked taps satisfy |jx-x|<=2, |jy-y|<=2 -> inside tile; clamp for masked
    int lx = min(max(jx - x0 + HALO, 0), TSX - 1);
    int ly = min(max(jy - y0 + HALO, 0), TSY - 1);
    lofs[t] = ly * TST + lx;
    okm |= ((unsigned)(inside && v1)) << t;
  }

  float vmn[12], vmx[12];
  int cbase = (ty + HALO) * TST + (tx + HALO);
  unsigned qc[3];
  #pragma unroll
  for (int c = 0; c < 3; ++c) {
    const float* t = &tile[c][0];
    float n00 = t[cbase - TST - 1], n01 = t[cbase - TST], n02 = t[cbase - TST + 1];
    float n10 = t[cbase - 1],       ctr = t[cbase],       n12 = t[cbase + 1];
    float n20 = t[cbase + TST - 1], n21 = t[cbase + TST], n22 = t[cbase + TST + 1];
    float a0 = -3.0f*n00 + 3.0f*n02 + 10.0f*n10 + 10.0f*n12 - 3.0f*n20 + 3.0f*n22;
    float a1 = -3.0f*n00 + 10.0f*n01 - 3.0f*n02 + 3.0f*n20 + 10.0f*n21 + 3.0f*n22;

    float m0 = (okm & 1u)   ? t[lofs[0]] : 0.0f;
    float m1 = (okm & 2u)   ? t[lofs[1]] : 0.0f;
    float m2 = (okm & 4u)   ? t[lofs[2]] : 0.0f;
    float m3 = (okm & 8u)   ? t[lofs[3]] : 0.0f;
    float m5 = (okm & 32u)  ? t[lofs[5]] : 0.0f;
    float m6 = (okm & 64u)  ? t[lofs[6]] : 0.0f;
    float m7 = (okm & 128u) ? t[lofs[7]] : 0.0f;
    float m8 = (okm & 256u) ? t[lofs[8]] : 0.0f;
    float r0 = -3.0f*m0 + 3.0f*m2 + 10.0f*m3 + 10.0f*m5 - 3.0f*m6 + 3.0f*m8;
    float r1 = -3.0f*m0 + 10.0f*m1 - 3.0f*m2 + 3.0f*m6 + 10.0f*m7 + 3.0f*m8;
    float b0 = valid2 ? r0 : 0.0f;
    float b1 = valid2 ? r1 : 0.0f;

    unsigned ua0 = bf16t(a0), ua1 = bf16t(a1), ub0 = bf16t(b0), ub1 = bf16t(b1);
    float a0r = bf16f(ua0), a1r = bf16f(ua1), b0r = bf16f(ub0), b1r = bf16f(ub1);

    grad2[(long)c * NPIX + p] = make_uint2(ua0 | (ua1 << 16), ub0 | (ub1 << 16));

    int cc = (int)(ctr * 24.0f);   // (img*(cb-1)).astype(int32)
    qc[c] = (unsigned)min(max(cc, 0), 24);

    vmn[2*c]     = a0r; vmx[2*c]     = a0r;
    vmn[2*c + 1] = a1r; vmx[2*c + 1] = a1r;
    vmn[6 + 2*c]     = b0r; vmx[6 + 2*c]     = b0r;
    vmn[6 + 2*c + 1] = b1r; vmx[6 + 2*c + 1] = b1r;
  }
  rkcp[p] = ((unsigned)rank << 14) | (qc[0] + 25u*qc[1] + 625u*qc[2]);

  #pragma unroll
  for (int off = 32; off >= 1; off >>= 1) {
    #pragma unroll
    for (int m = 0; m < 12; ++m) {
      vmn[m] = fminf(vmn[m], __shfl_xor(vmn[m], off));
      vmx[m] = fmaxf(vmx[m], __shfl_xor(vmx[m], off));
    }
  }
  __syncthreads();   // tile reads done before smn/smx overlay reuse is safe
  __shared__ float smn[12][4], smx[12][4];
  int wv = tid >> 6;
  if ((tid & 63) == 0) {
    #pragma unroll
    for (int m = 0; m < 12; ++m) { smn[m][wv] = vmn[m]; smx[m][wv] = vmx[m]; }
  }
  __syncthreads();
  if (tid < 12) {
    int m = tid;
    float mn = fminf(fminf(smn[m][0], smn[m][1]), fminf(smn[m][2], smn[m][3]));
    float mx = fmaxf(fmaxf(smx[m][0], smx[m][1]), fmaxf(smx[m][2], smx[m][3]));
    int fb = blockIdx.y * gridDim.x + blockIdx.x;
    pmin[m * NBLK_MM + fb] = mn;
    pmax[m * NBLK_MM + fb] = mx;
  }
}

// Fused: blocks 0..11 reduce one map's partials -> gmm; block 12 prefix-scans counts.
__global__ __launch_bounds__(1024) void k_redscan(const float* __restrict__ pmin,
                                                  const float* __restrict__ pmax,
                                                  const int* __restrict__ cnt,
                                                  float* __restrict__ gmm,
                                                  int* __restrict__ start) {
  int t = threadIdx.x;
  if (blockIdx.x < 12) {
    int m = blockIdx.x;
    float mn = FLT_MAX, mx = -FLT_MAX;
    #pragma unroll
    for (int j = 0; j < 4; ++j) {
      mn = fminf(mn, pmin[m * NBLK_MM + t + j * 1024]);
      mx = fmaxf(mx, pmax[m * NBLK_MM + t + j * 1024]);
    }
    #pragma unroll
    for (int off = 32; off >= 1; off >>= 1) {
      mn = fminf(mn, __shfl_xor(mn, off));
      mx = fmaxf(mx, __shfl_xor(mx, off));
    }
    __shared__ float smn[16], smx[16];
    int wv = t >> 6;
    if ((t & 63) == 0) { smn[wv] = mn; smx[wv] = mx; }
    __syncthreads();
    if (t == 0) {
      #pragma unroll
      for (int i = 1; i < 16; ++i) { mn = fminf(mn, smn[i]); mx = fmaxf(mx, smx[i]); }
      gmm[2*m] = mn; gmm[2*m + 1] = mx;
    }
    return;
  }
  // block 12: exclusive scan of 5000 counts
  __shared__ int part[1024];
  int base = t * 5;
  int v[5]; int sum = 0;
  #pragma unroll
  for (int j = 0; j < 5; ++j) {
    v[j] = (base + j < NBSEG) ? cnt[base + j] : 0;
    sum += v[j];
  }
  part[t] = sum;
  __syncthreads();
  #pragma unroll
  for (int d = 1; d < 1024; d <<= 1) {
    int xv = (t >= d) ? part[t - d] : 0;
    __syncthreads();
    part[t] += xv;
    __syncthreads();
  }
  int run = (t > 0) ? part[t - 1] : 0;   // exclusive
  #pragma unroll
  for (int j = 0; j < 5; ++j) {
    int i = base + j;
    if (i <= NBSEG) start[i] = run;
    run += v[j];
  }
}

// Pass 2: read bf16 grad planes + packed rank/color COALESCED, quantize
// (mul form, params from gmm in-block), pack 16B record, atomic-free scatter.
__global__ __launch_bounds__(256) void k_bin(const int* __restrict__ reg,
                                             const unsigned* __restrict__ rkcp,
                                             const int* __restrict__ start,
                                             const float* __restrict__ gmm,
                                             const uint2* __restrict__ grad2,
                                             uint4* __restrict__ rec) {
  __shared__ float params[48];
  if (threadIdx.x < 24) {
    int t = threadIdx.x;
    int c = t / 8, k = t % 8;
    int b = (k < 4) ? (2*c + (k & 1)) : (6 + 2*c + (k & 1));
    bool pos = ((k >> 1) & 1) == 0;   // k in {0,1,4,5} -> max(.,0); {2,3,6,7} -> min(.,0)
    float mn = gmm[2*b], mx = gmm[2*b + 1];
    float hmin, hmax;
    if (pos) { hmin = fmaxf(mn, 0.0f); hmax = fmaxf(mx, 0.0f); }
    else     { hmin = fminf(mn, 0.0f); hmax = fminf(mx, 0.0f); }
    params[2*t]     = hmin;
    params[2*t + 1] = 9.0f / (hmax - hmin);   // mul instead of div
  }
  __syncthreads();

  int p = blockIdx.x * 256 + threadIdx.x;
  int s = reg[p];
  if ((unsigned)s >= (unsigned)NBSEG) return;

  unsigned rc = rkcp[p];
  unsigned cp = rc & 0x3FFFu;
  unsigned rank = rc >> 14;

  unsigned q[24];
  #pragma unroll
  for (int c = 0; c < 3; ++c) {
    uint2 g = grad2[(long)c * NPIX + p];
    float gv[2] = { bf16f(g.x & 0xFFFFu), __uint_as_float(g.x & 0xFFFF0000u) };
    float rv[2] = { bf16f(g.y & 0xFFFFu), __uint_as_float(g.y & 0xFFFF0000u) };
    #pragma unroll
    for (int d = 0; d < 2; ++d) {
      {
        int m = c*8 + d;
        float v = fmaxf(gv[d], 0.0f);
        int qq = (int)((v - params[2*m]) * params[2*m + 1]);
        q[m] = (unsigned)min(max(qq, 0), 9);
      }
      {
        int m = c*8 + 2 + d;
        float v = fminf(gv[d], 0.0f);
        int qq = (int)((v - params[2*m]) * params[2*m + 1]);
        q[m] = (unsigned)min(max(qq, 0), 9);
      }
      {
        int m = c*8 + 4 + d;
        float v = fmaxf(rv[d], 0.0f);
        int qq = (int)((v - params[2*m]) * params[2*m + 1]);
        q[m] = (unsigned)min(max(qq, 0), 9);
      }
      {
        int m = c*8 + 6 + d;
        float v = fminf(rv[d], 0.0f);
        int qq = (int)((v - params[2*m]) * params[2*m + 1]);
        q[m] = (unsigned)min(max(qq, 0), 9);
      }
    }
  }

  unsigned trip[8];
  #pragma unroll
  for (int j = 0; j < 8; ++j)
    trip[j] = q[3*j] + 10u*q[3*j + 1] + 100u*q[3*j + 2];

  uint4 r;
  r.x = (unsigned)p | (trip[0] << 20);
  r.y = trip[1] | (trip[2] << 10) | (trip[3] << 20);
  r.z = trip[4] | (trip[5] << 10) | (trip[6] << 20);
  r.w = trip[7] | (cp << 10);

  rec[start[s] + rank] = r;   // atomic-free scatter
}

// One block per segment: STREAM the 16B records coalesced, bfe-unpack,
// ballot+popcount per (map,bin), lane-sliced register accumulate,
// one flush of 5 LDS atomics per wave. Shuffle-reduced bbox from packed p.
__global__ __launch_bounds__(256) void k_accum(const uint4* __restrict__ rec,
                                               const int* __restrict__ start,
                                               float* __restrict__ out) {
  __shared__ unsigned hist[316];
  __shared__ int bb[4];
  int tid = threadIdx.x;
  int lane = tid & 63;

  for (int i = tid; i < 316; i += 256) hist[i] = 0;
  if (tid == 0) { bb[0] = INT_MAX; bb[1] = INT_MAX; bb[2] = INT_MIN; bb[3] = INT_MIN; }
  __syncthreads();

  int s = blockIdx.x;
  int beg = start[s], end = start[s + 1];
  int n = end - beg;

  unsigned acc[5] = {0, 0, 0, 0, 0};   // lane-sliced: acc[j] counts bin (64*j + lane)
  int xmn = INT_MAX, ymn = INT_MAX, xmx = INT_MIN, ymx = INT_MIN;

  for (int base2 = beg; base2 < end; base2 += 256) {
    int i = base2 + tid;
    bool act = i < end;
    uint4 r = rec[act ? i : beg];
    unsigned inv = act ? 0u : 0xFFu;   // OR-mask pushes bins out of range for pad lanes

    unsigned tr[8];
    tr[0] = r.x >> 20;
    tr[1] = r.y & 0x3FFu; tr[2] = (r.y >> 10) & 0x3FFu; tr[3] = r.y >> 20;
    tr[4] = r.z & 0x3FFu; tr[5] = (r.z >> 10) & 0x3FFu; tr[6] = r.z >> 20;
    tr[7] = r.w & 0x3FFu;
    unsigned cp = r.w >> 10;

    unsigned qv[24];
    #pragma unroll
    for (int j = 0; j < 8; ++j) {
      unsigned t = tr[j];
      unsigned q2 = t / 100u; unsigned rr = t - 100u*q2;
      unsigned q1 = rr / 10u; unsigned q0 = rr - 10u*q1;
      qv[3*j]     = q0 | inv;
      qv[3*j + 1] = q1 | inv;
      qv[3*j + 2] = q2 | inv;
    }
    unsigned c0 = (cp % 25u) | inv;
    unsigned rem = cp / 25u;
    unsigned c1 = (rem % 25u) | inv;
    unsigned c2 = (rem / 25u) | inv;

    if (act) {
      unsigned p = r.x & 0xFFFFFu;
      int x = (int)(p & 1023u), y = (int)(p >> 10);
      xmn = min(xmn, x); ymn = min(ymn, y);
      xmx = max(xmx, x); ymx = max(ymx, y);
    }

    #pragma unroll
    for (int m = 0; m < 24; ++m) {
      #pragma unroll
      for (int b = 0; b < 10; ++b) {
        unsigned cntb = (unsigned)__popcll(__ballot(qv[m] == (unsigned)b));
        int idx = m * 10 + b;
        acc[idx >> 6] += (lane == (idx & 63)) ? cntb : 0u;
      }
    }
    unsigned qcs[3] = { c0, c1, c2 };
    #pragma unroll
    for (int cm = 0; cm < 3; ++cm) {
      #pragma unroll
      for (int b = 0; b < 25; ++b) {
        unsigned cntb = (unsigned)__popcll(__ballot(qcs[cm] == (unsigned)b));
        int idx = 240 + cm * 25 + b;
        acc[idx >> 6] += (lane == (idx & 63)) ? cntb : 0u;
      }
    }
  }

  #pragma unroll
  for (int j = 0; j < 5; ++j) {
    int idx = j * 64 + lane;
    if (idx < 315 && acc[j]) atomicAdd(&hist[idx], acc[j]);
  }

  #pragma unroll
  for (int off = 32; off >= 1; off >>= 1) {
    xmn = min(xmn, __shfl_xor(xmn, off));
    ymn = min(ymn, __shfl_xor(ymn, off));
    xmx = max(xmx, __shfl_xor(xmx, off));
    ymx = max(ymx, __shfl_xor(ymx, off));
  }
  if (lane == 0) {
    atomicMin(&bb[0], xmn); atomicMin(&bb[1], ymn);
    atomicMax(&bb[2], xmx); atomicMax(&bb[3], ymx);
  }
  __syncthreads();

  if (tid == 0) {
    out[4*s + 0] = (float)bb[0];
    out[4*s + 1] = (float)bb[1];
    out[4*s + 2] = (float)(bb[2] - bb[0]);
    out[4*s + 3] = (float)(bb[3] - bb[1]);
    out[OUT_SIZE_OFF + s] = (float)n;
  }
  bool ok = n > 0;
  float cden = 3.0f * (float)n, tden = 24.0f * (float)n;
  for (int i = tid; i < 240; i += 256)
    out[OUT_TEX_OFF + s*240 + i] = ok ? (float)hist[i] / tden : 0.0f;
  for (int i = tid; i < 75; i += 256)
    out[OUT_COLOR_OFF + s*75 + i] = ok ? (float)hist[240 + i] / cden : 0.0f;
}

// ---------------- launch ----------------

extern "C" void kernel_launch(void* const* d_in, const int* in_sizes, int n_in,
                              void* d_out, int out_size, void* d_ws, size_t ws_size,
                              hipStream_t stream) {
  const float* img = (const float*)d_in[0];
  const int*   reg = (const int*)d_in[1];
  float* out = (float*)d_out;

  char* ws = (char*)d_ws;
  size_t off = 0;
  uint2*    grad2 = (uint2*)(ws + off);    off += (size_t)3 * NPIX * 8;       off = (off + 255) & ~(size_t)255;
  uint4*    rec   = (uint4*)(ws + off);    off += (size_t)(NPIX + 256) * 16;  off = (off + 255) & ~(size_t)255;
  unsigned* rkcp  = (unsigned*)(ws + off); off += (size_t)NPIX * 4;           off = (off + 255) & ~(size_t)255;
  int*      cnt   = (int*)(ws + off);      off += 5120 * 4;
  int*      start = (int*)(ws + off);      off += 5008 * 4;
  float*    gmm   = (float*)(ws + off);    off += 32 * 4;                     off = (off + 255) & ~(size_t)255;
  float*    pmin  = (float*)(ws + off);    off += (size_t)12 * NBLK_MM * 4;
  float*    pmax  = (float*)(ws + off);    off += (size_t)12 * NBLK_MM * 4;
  (void)ws_size; (void)in_sizes; (void)n_in; (void)out_size;

  double th  = 45.0 * (M_PI / 180.0);
  float cf = (float)cos(th),  sf = (float)sin(th);    // forward +45
  double thb = -45.0 * (M_PI / 180.0);
  float cbk = (float)cos(thb), sbk = (float)sin(thb); // backward -45

  dim3 gMM(WW / TW, HH / TH);   // 16 x 256 = 4096 blocks

  hipMemsetAsync(cnt, 0, 5120 * sizeof(int), stream);
  k_mm     <<<gMM,       256,  0, stream>>>(img, reg, cnt, rkcp, grad2, pmin, pmax, cbk, sbk, cf, sf);
  k_redscan<<<13,        1024, 0, stream>>>(pmin, pmax, cnt, gmm, start);
  k_bin    <<<NPIX/256,  256,  0, stream>>>(reg, rkcp, start, gmm, grad2, rec);
  k_accum  <<<NBSEG,     256,  0, stream>>>(rec, start, out);
}

// Round 20
// 206.262 us; speedup vs baseline: 1.0623x; 1.0484x over previous
//
#include <hip/hip_runtime.h>
#include <math.h>
#include <float.h>
#include <limits.h>

// ---------------- problem constants (fixed by setup_inputs) ----------------
#define HH 1024
#define WW 1024
#define NPIX (HH*WW)          // 1048576
#define RH 1449               // ceil(1024*sqrt(2))
#define RW 1449
#define NBSEG 5000
#define START 211             // int((rot_bbox_w - 1024)/2) for 45 deg

// k_mm tiling (r17 config — best measured): 64x4 px/block, 1 px/thread, halo 3
#define TW 64
#define TH 4
#define HALO 3
#define TSX (TW + 2*HALO)     // 70
#define TSY (TH + 2*HALO)     // 10
#define TST 71                // padded LDS row stride
#define NBLK_MM 4096          // (1024/64) x (1024/4)

// padded segment counters: one per 64B cache line (L2 same-line RMW chains
// are the suspected k_mm floor: 1M atomics / 313 lines = ~3200 RMW per line)
#define CNT_STRIDE 16         // ints per counter slot (64 B)

// output layout (floats, concatenated in return order)
#define OUT_XYWH_OFF  0          // 5000*4
#define OUT_SIZE_OFF  20000      // 5000
#define OUT_COLOR_OFF 25000      // 5000*3*25
#define OUT_TEX_OFF   400000     // 5000*3*8*10
#define OUT_TOTAL     1600000

__device__ __forceinline__ unsigned bf16t(float v) { return __float_as_uint(v) >> 16; }
__device__ __forceinline__ float bf16f(unsigned h) { return __uint_as_float(h << 16); }

// ---------------- kernels ----------------

// Pass 1 (r17 structure): zero-padded 70x10x3 img tile in LDS; stencil + rot
// taps all LDS. rank and color-bin packed into ONE int plane:
// rkcp[p] = (rank << 14) | cpq.  Counters line-padded (cnt[s*16]).
__global__ __launch_bounds__(256, 6) void k_mm(const float* __restrict__ img,
                                               const int* __restrict__ reg,
                                               int* __restrict__ cnt,
                                               unsigned* __restrict__ rkcp,
                                               uint2* __restrict__ grad2,
                                               float* __restrict__ pmin,
                                               float* __restrict__ pmax,
                                               float cb, float sb, float cf, float sf) {
  __shared__ float tile[3][TSY * TST];
  int tid = threadIdx.x;
  int x0 = blockIdx.x * TW, y0 = blockIdx.y * TH;

  // coalesced zero-padded tile load (rows of 70; lanes consecutive)
  for (int i = tid; i < 3 * TSY * TSX; i += 256) {
    int c = i / (TSY * TSX); int r = i - c * (TSY * TSX);
    int ly = r / TSX, lx = r - ly * TSX;
    int gx = x0 - HALO + lx, gy = y0 - HALO + ly;
    float v = ((unsigned)gx < (unsigned)WW && (unsigned)gy < (unsigned)HH)
              ? img[(long)c * NPIX + (long)gy * WW + gx] : 0.0f;
    tile[c][ly * TST + lx] = v;
  }
  __syncthreads();

  int tx = tid & 63, ty = tid >> 6;
  int x = x0 + tx, y = y0 + ty;
  int p = y * WW + x;
  int s = reg[p];
  int rank = ((unsigned)s < (unsigned)NBSEG) ? atomicAdd(&cnt[s * CNT_STRIDE], 1) : 0;

  // ---- back-map center (exact expressions, as all passing rounds)
  float sx, sy;
  {
    #pragma clang fp contract(off)
    float dx = (float)(x + START) - 1024.5f;   // ncx of 2050-grid
    float dy = (float)(y + START) - 1024.5f;
    sx = cb*dx - sb*dy + 724.0f;               // cx of 1449-grid
    sy = sb*dx + cb*dy + 724.0f;
  }
  bool valid2 = (sx >= -0.5f) && (sx <= (float)RW - 0.5f) &&
                (sy >= -0.5f) && (sy <= (float)RH - 0.5f);
  int ix = min(max((int)rintf(sx), 0), RW - 1);
  int iy = min(max((int)rintf(sy), 0), RH - 1);

  float fxc, fyc;
  {
    #pragma clang fp contract(off)
    float ddx = (float)ix - 724.0f;
    float ddy = (float)iy - 724.0f;
    fxc = cf*ddx - sf*ddy + 511.5f;
    fyc = sf*ddx + cf*ddy + 511.5f;
  }

  int lofs[9];              // LDS-local tap offsets (valid when okm bit set)
  unsigned okm = 0;
  #pragma unroll
  for (int t = 0; t < 9; ++t) {
    const int dxi = (t % 3) - 1, dyi = (t / 3) - 1;
    int rx = ix + dxi, ry = iy + dyi;
    bool inside = ((unsigned)rx < (unsigned)RW) && ((unsigned)ry < (unsigned)RH);
    float fx = fxc + (cf*(float)dxi - sf*(float)dyi);   // scalar-folded constants
    float fy = fyc + (sf*(float)dxi + cf*(float)dyi);
    bool v1 = (fx >= -0.5f) && (fx <= 1023.5f) && (fy >= -0.5f) && (fy <= 1023.5f);
    int jx = min(max((int)rintf(fx), 0), WW - 1);
    int jy = min(max((int)rintf(fy), 0), HH - 1);
    // unmasked taps satisfy |jx-x|<=2, |jy-y|<=2 -> inside tile; clamp for masked
    int lx = min(max(jx - x0 + HALO, 0), TSX - 1);
    int ly = min(max(jy - y0 + HALO, 0), TSY - 1);
    lofs[t] = ly * TST + lx;
    okm |= ((unsigned)(inside && v1)) << t;
  }

  float vmn[12], vmx[12];
  int cbase = (ty + HALO) * TST + (tx + HALO);
  unsigned qc[3];
  #pragma unroll
  for (int c = 0; c < 3; ++c) {
    const float* t = &tile[c][0];
    float n00 = t[cbase - TST - 1], n01 = t[cbase - TST], n02 = t[cbase - TST + 1];
    float n10 = t[cbase - 1],       ctr = t[cbase],       n12 = t[cbase + 1];
    float n20 = t[cbase + TST - 1], n21 = t[cbase + TST], n22 = t[cbase + TST + 1];
    float a0 = -3.0f*n00 + 3.0f*n02 + 10.0f*n10 + 10.0f*n12 - 3.0f*n20 + 3.0f*n22;
    float a1 = -3.0f*n00 + 10.0f*n01 - 3.0f*n02 + 3.0f*n20 + 10.0f*n21 + 3.0f*n22;

    float m0 = (okm & 1u)   ? t[lofs[0]] : 0.0f;
    float m1 = (okm & 2u)   ? t[lofs[1]] : 0.0f;
    float m2 = (okm & 4u)   ? t[lofs[2]] : 0.0f;
    float m3 = (okm & 8u)   ? t[lofs[3]] : 0.0f;
    float m5 = (okm & 32u)  ? t[lofs[5]] : 0.0f;
    float m6 = (okm & 64u)  ? t[lofs[6]] : 0.0f;
    float m7 = (okm & 128u) ? t[lofs[7]] : 0.0f;
    float m8 = (okm & 256u) ? t[lofs[8]] : 0.0f;
    float r0 = -3.0f*m0 + 3.0f*m2 + 10.0f*m3 + 10.0f*m5 - 3.0f*m6 + 3.0f*m8;
    float r1 = -3.0f*m0 + 10.0f*m1 - 3.0f*m2 + 3.0f*m6 + 10.0f*m7 + 3.0f*m8;
    float b0 = valid2 ? r0 : 0.0f;
    float b1 = valid2 ? r1 : 0.0f;

    unsigned ua0 = bf16t(a0), ua1 = bf16t(a1), ub0 = bf16t(b0), ub1 = bf16t(b1);
    float a0r = bf16f(ua0), a1r = bf16f(ua1), b0r = bf16f(ub0), b1r = bf16f(ub1);

    grad2[(long)c * NPIX + p] = make_uint2(ua0 | (ua1 << 16), ub0 | (ub1 << 16));

    int cc = (int)(ctr * 24.0f);   // (img*(cb-1)).astype(int32)
    qc[c] = (unsigned)min(max(cc, 0), 24);

    vmn[2*c]     = a0r; vmx[2*c]     = a0r;
    vmn[2*c + 1] = a1r; vmx[2*c + 1] = a1r;
    vmn[6 + 2*c]     = b0r; vmx[6 + 2*c]     = b0r;
    vmn[6 + 2*c + 1] = b1r; vmx[6 + 2*c + 1] = b1r;
  }
  rkcp[p] = ((unsigned)rank << 14) | (qc[0] + 25u*qc[1] + 625u*qc[2]);

  #pragma unroll
  for (int off = 32; off >= 1; off >>= 1) {
    #pragma unroll
    for (int m = 0; m < 12; ++m) {
      vmn[m] = fminf(vmn[m], __shfl_xor(vmn[m], off));
      vmx[m] = fmaxf(vmx[m], __shfl_xor(vmx[m], off));
    }
  }
  __syncthreads();   // tile reads done before smn/smx overlay reuse is safe
  __shared__ float smn[12][4], smx[12][4];
  int wv = tid >> 6;
  if ((tid & 63) == 0) {
    #pragma unroll
    for (int m = 0; m < 12; ++m) { smn[m][wv] = vmn[m]; smx[m][wv] = vmx[m]; }
  }
  __syncthreads();
  if (tid < 12) {
    int m = tid;
    float mn = fminf(fminf(smn[m][0], smn[m][1]), fminf(smn[m][2], smn[m][3]));
    float mx = fmaxf(fmaxf(smx[m][0], smx[m][1]), fmaxf(smx[m][2], smx[m][3]));
    int fb = blockIdx.y * gridDim.x + blockIdx.x;
    pmin[m * NBLK_MM + fb] = mn;
    pmax[m * NBLK_MM + fb] = mx;
  }
}

// Fused: blocks 0..11 reduce one map's partials -> gmm; block 12 prefix-scans counts.
__global__ __launch_bounds__(1024) void k_redscan(const float* __restrict__ pmin,
                                                  const float* __restrict__ pmax,
                                                  const int* __restrict__ cnt,
                                                  float* __restrict__ gmm,
                                                  int* __restrict__ start) {
  int t = threadIdx.x;
  if (blockIdx.x < 12) {
    int m = blockIdx.x;
    float mn = FLT_MAX, mx = -FLT_MAX;
    #pragma unroll
    for (int j = 0; j < 4; ++j) {
      mn = fminf(mn, pmin[m * NBLK_MM + t + j * 1024]);
      mx = fmaxf(mx, pmax[m * NBLK_MM + t + j * 1024]);
    }
    #pragma unroll
    for (int off = 32; off >= 1; off >>= 1) {
      mn = fminf(mn, __shfl_xor(mn, off));
      mx = fmaxf(mx, __shfl_xor(mx, off));
    }
    __shared__ float smn[16], smx[16];
    int wv = t >> 6;
    if ((t & 63) == 0) { smn[wv] = mn; smx[wv] = mx; }
    __syncthreads();
    if (t == 0) {
      #pragma unroll
      for (int i = 1; i < 16; ++i) { mn = fminf(mn, smn[i]); mx = fmaxf(mx, smx[i]); }
      gmm[2*m] = mn; gmm[2*m + 1] = mx;
    }
    return;
  }
  // block 12: exclusive scan of 5000 line-padded counts
  __shared__ int part[1024];
  int base = t * 5;
  int v[5]; int sum = 0;
  #pragma unroll
  for (int j = 0; j < 5; ++j) {
    v[j] = (base + j < NBSEG) ? cnt[(base + j) * CNT_STRIDE] : 0;
    sum += v[j];
  }
  part[t] = sum;
  __syncthreads();
  #pragma unroll
  for (int d = 1; d < 1024; d <<= 1) {
    int xv = (t >= d) ? part[t - d] : 0;
    __syncthreads();
    part[t] += xv;
    __syncthreads();
  }
  int run = (t > 0) ? part[t - 1] : 0;   // exclusive
  #pragma unroll
  for (int j = 0; j < 5; ++j) {
    int i = base + j;
    if (i <= NBSEG) start[i] = run;
    run += v[j];
  }
}

// Pass 2: read bf16 grad planes + packed rank/color COALESCED, quantize
// (mul form, params from gmm in-block), pack 16B record, atomic-free scatter.
__global__ __launch_bounds__(256) void k_bin(const int* __restrict__ reg,
                                             const unsigned* __restrict__ rkcp,
                                             const int* __restrict__ start,
                                             const float* __restrict__ gmm,
                                             const uint2* __restrict__ grad2,
                                             uint4* __restrict__ rec) {
  __shared__ float params[48];
  if (threadIdx.x < 24) {
    int t = threadIdx.x;
    int c = t / 8, k = t % 8;
    int b = (k < 4) ? (2*c + (k & 1)) : (6 + 2*c + (k & 1));
    bool pos = ((k >> 1) & 1) == 0;   // k in {0,1,4,5} -> max(.,0); {2,3,6,7} -> min(.,0)
    float mn = gmm[2*b], mx = gmm[2*b + 1];
    float hmin, hmax;
    if (pos) { hmin = fmaxf(mn, 0.0f); hmax = fmaxf(mx, 0.0f); }
    else     { hmin = fminf(mn, 0.0f); hmax = fminf(mx, 0.0f); }
    params[2*t]     = hmin;
    params[2*t + 1] = 9.0f / (hmax - hmin);   // mul instead of div
  }
  __syncthreads();

  int p = blockIdx.x * 256 + threadIdx.x;
  int s = reg[p];
  if ((unsigned)s >= (unsigned)NBSEG) return;

  unsigned rc = rkcp[p];
  unsigned cp = rc & 0x3FFFu;
  unsigned rank = rc >> 14;

  unsigned q[24];
  #pragma unroll
  for (int c = 0; c < 3; ++c) {
    uint2 g = grad2[(long)c * NPIX + p];
    float gv[2] = { bf16f(g.x & 0xFFFFu), __uint_as_float(g.x & 0xFFFF0000u) };
    float rv[2] = { bf16f(g.y & 0xFFFFu), __uint_as_float(g.y & 0xFFFF0000u) };
    #pragma unroll
    for (int d = 0; d < 2; ++d) {
      {
        int m = c*8 + d;
        float v = fmaxf(gv[d], 0.0f);
        int qq = (int)((v - params[2*m]) * params[2*m + 1]);
        q[m] = (unsigned)min(max(qq, 0), 9);
      }
      {
        int m = c*8 + 2 + d;
        float v = fminf(gv[d], 0.0f);
        int qq = (int)((v - params[2*m]) * params[2*m + 1]);
        q[m] = (unsigned)min(max(qq, 0), 9);
      }
      {
        int m = c*8 + 4 + d;
        float v = fmaxf(rv[d], 0.0f);
        int qq = (int)((v - params[2*m]) * params[2*m + 1]);
        q[m] = (unsigned)min(max(qq, 0), 9);
      }
      {
        int m = c*8 + 6 + d;
        float v = fminf(rv[d], 0.0f);
        int qq = (int)((v - params[2*m]) * params[2*m + 1]);
        q[m] = (unsigned)min(max(qq, 0), 9);
      }
    }
  }

  unsigned trip[8];
  #pragma unroll
  for (int j = 0; j < 8; ++j)
    trip[j] = q[3*j] + 10u*q[3*j + 1] + 100u*q[3*j + 2];

  uint4 r;
  r.x = (unsigned)p | (trip[0] << 20);
  r.y = trip[1] | (trip[2] << 10) | (trip[3] << 20);
  r.z = trip[4] | (trip[5] << 10) | (trip[6] << 20);
  r.w = trip[7] | (cp << 10);

  rec[start[s] + rank] = r;   // atomic-free scatter
}

// One block per segment: STREAM the 16B records coalesced, bfe-unpack,
// ballot+popcount per (map,bin), lane-sliced register accumulate,
// one flush of 5 LDS atomics per wave. Shuffle-reduced bbox from packed p.
__global__ __launch_bounds__(256) void k_accum(const uint4* __restrict__ rec,
                                               const int* __restrict__ start,
                                               float* __restrict__ out) {
  __shared__ unsigned hist[316];
  __shared__ int bb[4];
  int tid = threadIdx.x;
  int lane = tid & 63;

  for (int i = tid; i < 316; i += 256) hist[i] = 0;
  if (tid == 0) { bb[0] = INT_MAX; bb[1] = INT_MAX; bb[2] = INT_MIN; bb[3] = INT_MIN; }
  __syncthreads();

  int s = blockIdx.x;
  int beg = start[s], end = start[s + 1];
  int n = end - beg;

  unsigned acc[5] = {0, 0, 0, 0, 0};   // lane-sliced: acc[j] counts bin (64*j + lane)
  int xmn = INT_MAX, ymn = INT_MAX, xmx = INT_MIN, ymx = INT_MIN;

  for (int base2 = beg; base2 < end; base2 += 256) {
    int i = base2 + tid;
    bool act = i < end;
    uint4 r = rec[act ? i : beg];
    unsigned inv = act ? 0u : 0xFFu;   // OR-mask pushes bins out of range for pad lanes

    unsigned tr[8];
    tr[0] = r.x >> 20;
    tr[1] = r.y & 0x3FFu; tr[2] = (r.y >> 10) & 0x3FFu; tr[3] = r.y >> 20;
    tr[4] = r.z & 0x3FFu; tr[5] = (r.z >> 10) & 0x3FFu; tr[6] = r.z >> 20;
    tr[7] = r.w & 0x3FFu;
    unsigned cp = r.w >> 10;

    unsigned qv[24];
    #pragma unroll
    for (int j = 0; j < 8; ++j) {
      unsigned t = tr[j];
      unsigned q2 = t / 100u; unsigned rr = t - 100u*q2;
      unsigned q1 = rr / 10u; unsigned q0 = rr - 10u*q1;
      qv[3*j]     = q0 | inv;
      qv[3*j + 1] = q1 | inv;
      qv[3*j + 2] = q2 | inv;
    }
    unsigned c0 = (cp % 25u) | inv;
    unsigned rem = cp / 25u;
    unsigned c1 = (rem % 25u) | inv;
    unsigned c2 = (rem / 25u) | inv;

    if (act) {
      unsigned p = r.x & 0xFFFFFu;
      int x = (int)(p & 1023u), y = (int)(p >> 10);
      xmn = min(xmn, x); ymn = min(ymn, y);
      xmx = max(xmx, x); ymx = max(ymx, y);
    }

    #pragma unroll
    for (int m = 0; m < 24; ++m) {
      #pragma unroll
      for (int b = 0; b < 10; ++b) {
        unsigned cntb = (unsigned)__popcll(__ballot(qv[m] == (unsigned)b));
        int idx = m * 10 + b;
        acc[idx >> 6] += (lane == (idx & 63)) ? cntb : 0u;
      }
    }
    unsigned qcs[3] = { c0, c1, c2 };
    #pragma unroll
    for (int cm = 0; cm < 3; ++cm) {
      #pragma unroll
      for (int b = 0; b < 25; ++b) {
        unsigned cntb = (unsigned)__popcll(__ballot(qcs[cm] == (unsigned)b));
        int idx = 240 + cm * 25 + b;
        acc[idx >> 6] += (lane == (idx & 63)) ? cntb : 0u;
      }
    }
  }

  #pragma unroll
  for (int j = 0; j < 5; ++j) {
    int idx = j * 64 + lane;
    if (idx < 315 && acc[j]) atomicAdd(&hist[idx], acc[j]);
  }

  #pragma unroll
  for (int off = 32; off >= 1; off >>= 1) {
    xmn = min(xmn, __shfl_xor(xmn, off));
    ymn = min(ymn, __shfl_xor(ymn, off));
    xmx = max(xmx, __shfl_xor(xmx, off));
    ymx = max(ymx, __shfl_xor(ymx, off));
  }
  if (lane == 0) {
    atomicMin(&bb[0], xmn); atomicMin(&bb[1], ymn);
    atomicMax(&bb[2], xmx); atomicMax(&bb[3], ymx);
  }
  __syncthreads();

  if (tid == 0) {
    out[4*s + 0] = (float)bb[0];
    out[4*s + 1] = (float)bb[1];
    out[4*s + 2] = (float)(bb[2] - bb[0]);
    out[4*s + 3] = (float)(bb[3] - bb[1]);
    out[OUT_SIZE_OFF + s] = (float)n;
  }
  bool ok = n > 0;
  float cden = 3.0f * (float)n, tden = 24.0f * (float)n;
  for (int i = tid; i < 240; i += 256)
    out[OUT_TEX_OFF + s*240 + i] = ok ? (float)hist[i] / tden : 0.0f;
  for (int i = tid; i < 75; i += 256)
    out[OUT_COLOR_OFF + s*75 + i] = ok ? (float)hist[240 + i] / cden : 0.0f;
}

// ---------------- launch ----------------

extern "C" void kernel_launch(void* const* d_in, const int* in_sizes, int n_in,
                              void* d_out, int out_size, void* d_ws, size_t ws_size,
                              hipStream_t stream) {
  const float* img = (const float*)d_in[0];
  const int*   reg = (const int*)d_in[1];
  float* out = (float*)d_out;

  char* ws = (char*)d_ws;
  size_t off = 0;
  uint2*    grad2 = (uint2*)(ws + off);    off += (size_t)3 * NPIX * 8;       off = (off + 255) & ~(size_t)255;
  uint4*    rec   = (uint4*)(ws + off);    off += (size_t)(NPIX + 256) * 16;  off = (off + 255) & ~(size_t)255;
  unsigned* rkcp  = (unsigned*)(ws + off); off += (size_t)NPIX * 4;           off = (off + 255) & ~(size_t)255;
  int*      cnt   = (int*)(ws + off);      off += (size_t)5008 * CNT_STRIDE * 4;
  int*      start = (int*)(ws + off);      off += 5008 * 4;
  float*    gmm   = (float*)(ws + off);    off += 32 * 4;                     off = (off + 255) & ~(size_t)255;
  float*    pmin  = (float*)(ws + off);    off += (size_t)12 * NBLK_MM * 4;
  float*    pmax  = (float*)(ws + off);    off += (size_t)12 * NBLK_MM * 4;
  (void)ws_size; (void)in_sizes; (void)n_in; (void)out_size;

  double th  = 45.0 * (M_PI / 180.0);
  float cf = (float)cos(th),  sf = (float)sin(th);    // forward +45
  double thb = -45.0 * (M_PI / 180.0);
  float cbk = (float)cos(thb), sbk = (float)sin(thb); // backward -45

  dim3 gMM(WW / TW, HH / TH);   // 16 x 256 = 4096 blocks

  hipMemsetAsync(cnt, 0, (size_t)5008 * CNT_STRIDE * 4, stream);
  k_mm     <<<gMM,       256,  0, stream>>>(img, reg, cnt, rkcp, grad2, pmin, pmax, cbk, sbk, cf, sf);
  k_redscan<<<13,        1024, 0, stream>>>(pmin, pmax, cnt, gmm, start);
  k_bin    <<<NPIX/256,  256,  0, stream>>>(reg, rkcp, start, gmm, grad2, rec);
  k_accum  <<<NBSEG,     256,  0, stream>>>(rec, start, out);
}

// Round 21
// 204.481 us; speedup vs baseline: 1.0715x; 1.0087x over previous
//
#include <hip/hip_runtime.h>
#include <math.h>
#include <float.h>
#include <limits.h>

// ---------------- problem constants (fixed by setup_inputs) ----------------
#define HH 1024
#define WW 1024
#define NPIX (HH*WW)          // 1048576
#define RH 1449               // ceil(1024*sqrt(2))
#define RW 1449
#define NBSEG 5000
#define START 211             // int((rot_bbox_w - 1024)/2) for 45 deg

// k_mm tiling (r17 config — best measured): 64x4 px/block, 1 px/thread, halo 3
#define TW 64
#define TH 4
#define HALO 3
#define TSX (TW + 2*HALO)     // 70
#define TSY (TH + 2*HALO)     // 10
#define TST 71                // padded LDS row stride
#define NBLK_MM 4096          // (1024/64) x (1024/4)

// line-padded segment counters (r20 WIN: k_mm 74->60 us; L2 same-line RMW chains)
#define CNT_STRIDE 16         // ints per counter slot (64 B)

// output layout (floats, concatenated in return order)
#define OUT_XYWH_OFF  0          // 5000*4
#define OUT_SIZE_OFF  20000      // 5000
#define OUT_COLOR_OFF 25000      // 5000*3*25
#define OUT_TEX_OFF   400000     // 5000*3*8*10
#define OUT_TOTAL     1600000

__device__ __forceinline__ unsigned bf16t(float v) { return __float_as_uint(v) >> 16; }
__device__ __forceinline__ float bf16f(unsigned h) { return __uint_as_float(h << 16); }

// ---------------- kernels ----------------

// Pass 1 (r17 structure): zero-padded 70x10x3 img tile in LDS; stencil + rot
// taps all LDS. rank and color-bin packed into ONE int plane:
// rkcp[p] = (rank << 14) | cpq.  Counters line-padded (cnt[s*16]).
__global__ __launch_bounds__(256, 6) void k_mm(const float* __restrict__ img,
                                               const int* __restrict__ reg,
                                               int* __restrict__ cnt,
                                               unsigned* __restrict__ rkcp,
                                               uint2* __restrict__ grad2,
                                               float* __restrict__ pmin,
                                               float* __restrict__ pmax,
                                               float cb, float sb, float cf, float sf) {
  __shared__ float tile[3][TSY * TST];
  int tid = threadIdx.x;
  int x0 = blockIdx.x * TW, y0 = blockIdx.y * TH;

  for (int i = tid; i < 3 * TSY * TSX; i += 256) {
    int c = i / (TSY * TSX); int r = i - c * (TSY * TSX);
    int ly = r / TSX, lx = r - ly * TSX;
    int gx = x0 - HALO + lx, gy = y0 - HALO + ly;
    float v = ((unsigned)gx < (unsigned)WW && (unsigned)gy < (unsigned)HH)
              ? img[(long)c * NPIX + (long)gy * WW + gx] : 0.0f;
    tile[c][ly * TST + lx] = v;
  }
  __syncthreads();

  int tx = tid & 63, ty = tid >> 6;
  int x = x0 + tx, y = y0 + ty;
  int p = y * WW + x;
  int s = reg[p];
  int rank = ((unsigned)s < (unsigned)NBSEG) ? atomicAdd(&cnt[s * CNT_STRIDE], 1) : 0;

  float sx, sy;
  {
    #pragma clang fp contract(off)
    float dx = (float)(x + START) - 1024.5f;   // ncx of 2050-grid
    float dy = (float)(y + START) - 1024.5f;
    sx = cb*dx - sb*dy + 724.0f;               // cx of 1449-grid
    sy = sb*dx + cb*dy + 724.0f;
  }
  bool valid2 = (sx >= -0.5f) && (sx <= (float)RW - 0.5f) &&
                (sy >= -0.5f) && (sy <= (float)RH - 0.5f);
  int ix = min(max((int)rintf(sx), 0), RW - 1);
  int iy = min(max((int)rintf(sy), 0), RH - 1);

  float fxc, fyc;
  {
    #pragma clang fp contract(off)
    float ddx = (float)ix - 724.0f;
    float ddy = (float)iy - 724.0f;
    fxc = cf*ddx - sf*ddy + 511.5f;
    fyc = sf*ddx + cf*ddy + 511.5f;
  }

  int lofs[9];
  unsigned okm = 0;
  #pragma unroll
  for (int t = 0; t < 9; ++t) {
    const int dxi = (t % 3) - 1, dyi = (t / 3) - 1;
    int rx = ix + dxi, ry = iy + dyi;
    bool inside = ((unsigned)rx < (unsigned)RW) && ((unsigned)ry < (unsigned)RH);
    float fx = fxc + (cf*(float)dxi - sf*(float)dyi);
    float fy = fyc + (sf*(float)dxi + cf*(float)dyi);
    bool v1 = (fx >= -0.5f) && (fx <= 1023.5f) && (fy >= -0.5f) && (fy <= 1023.5f);
    int jx = min(max((int)rintf(fx), 0), WW - 1);
    int jy = min(max((int)rintf(fy), 0), HH - 1);
    int lx = min(max(jx - x0 + HALO, 0), TSX - 1);
    int ly = min(max(jy - y0 + HALO, 0), TSY - 1);
    lofs[t] = ly * TST + lx;
    okm |= ((unsigned)(inside && v1)) << t;
  }

  float vmn[12], vmx[12];
  int cbase = (ty + HALO) * TST + (tx + HALO);
  unsigned qc[3];
  #pragma unroll
  for (int c = 0; c < 3; ++c) {
    const float* t = &tile[c][0];
    float n00 = t[cbase - TST - 1], n01 = t[cbase - TST], n02 = t[cbase - TST + 1];
    float n10 = t[cbase - 1],       ctr = t[cbase],       n12 = t[cbase + 1];
    float n20 = t[cbase + TST - 1], n21 = t[cbase + TST], n22 = t[cbase + TST + 1];
    float a0 = -3.0f*n00 + 3.0f*n02 + 10.0f*n10 + 10.0f*n12 - 3.0f*n20 + 3.0f*n22;
    float a1 = -3.0f*n00 + 10.0f*n01 - 3.0f*n02 + 3.0f*n20 + 10.0f*n21 + 3.0f*n22;

    float m0 = (okm & 1u)   ? t[lofs[0]] : 0.0f;
    float m1 = (okm & 2u)   ? t[lofs[1]] : 0.0f;
    float m2 = (okm & 4u)   ? t[lofs[2]] : 0.0f;
    float m3 = (okm & 8u)   ? t[lofs[3]] : 0.0f;
    float m5 = (okm & 32u)  ? t[lofs[5]] : 0.0f;
    float m6 = (okm & 64u)  ? t[lofs[6]] : 0.0f;
    float m7 = (okm & 128u) ? t[lofs[7]] : 0.0f;
    float m8 = (okm & 256u) ? t[lofs[8]] : 0.0f;
    float r0 = -3.0f*m0 + 3.0f*m2 + 10.0f*m3 + 10.0f*m5 - 3.0f*m6 + 3.0f*m8;
    float r1 = -3.0f*m0 + 10.0f*m1 - 3.0f*m2 + 3.0f*m6 + 10.0f*m7 + 3.0f*m8;
    float b0 = valid2 ? r0 : 0.0f;
    float b1 = valid2 ? r1 : 0.0f;

    unsigned ua0 = bf16t(a0), ua1 = bf16t(a1), ub0 = bf16t(b0), ub1 = bf16t(b1);
    float a0r = bf16f(ua0), a1r = bf16f(ua1), b0r = bf16f(ub0), b1r = bf16f(ub1);

    grad2[(long)c * NPIX + p] = make_uint2(ua0 | (ua1 << 16), ub0 | (ub1 << 16));

    int cc = (int)(ctr * 24.0f);   // (img*(cb-1)).astype(int32)
    qc[c] = (unsigned)min(max(cc, 0), 24);

    vmn[2*c]     = a0r; vmx[2*c]     = a0r;
    vmn[2*c + 1] = a1r; vmx[2*c + 1] = a1r;
    vmn[6 + 2*c]     = b0r; vmx[6 + 2*c]     = b0r;
    vmn[6 + 2*c + 1] = b1r; vmx[6 + 2*c + 1] = b1r;
  }
  rkcp[p] = ((unsigned)rank << 14) | (qc[0] + 25u*qc[1] + 625u*qc[2]);

  #pragma unroll
  for (int off = 32; off >= 1; off >>= 1) {
    #pragma unroll
    for (int m = 0; m < 12; ++m) {
      vmn[m] = fminf(vmn[m], __shfl_xor(vmn[m], off));
      vmx[m] = fmaxf(vmx[m], __shfl_xor(vmx[m], off));
    }
  }
  __syncthreads();
  __shared__ float smn[12][4], smx[12][4];
  int wv = tid >> 6;
  if ((tid & 63) == 0) {
    #pragma unroll
    for (int m = 0; m < 12; ++m) { smn[m][wv] = vmn[m]; smx[m][wv] = vmx[m]; }
  }
  __syncthreads();
  if (tid < 12) {
    int m = tid;
    float mn = fminf(fminf(smn[m][0], smn[m][1]), fminf(smn[m][2], smn[m][3]));
    float mx = fmaxf(fmaxf(smx[m][0], smx[m][1]), fmaxf(smx[m][2], smx[m][3]));
    int fb = blockIdx.y * gridDim.x + blockIdx.x;
    pmin[m * NBLK_MM + fb] = mn;
    pmax[m * NBLK_MM + fb] = mx;
  }
}

// Fused: blocks 0..11 reduce one map's partials -> gmm; block 12 prefix-scans counts.
__global__ __launch_bounds__(1024) void k_redscan(const float* __restrict__ pmin,
                                                  const float* __restrict__ pmax,
                                                  const int* __restrict__ cnt,
                                                  float* __restrict__ gmm,
                                                  int* __restrict__ start) {
  int t = threadIdx.x;
  if (blockIdx.x < 12) {
    int m = blockIdx.x;
    float mn = FLT_MAX, mx = -FLT_MAX;
    #pragma unroll
    for (int j = 0; j < 4; ++j) {
      mn = fminf(mn, pmin[m * NBLK_MM + t + j * 1024]);
      mx = fmaxf(mx, pmax[m * NBLK_MM + t + j * 1024]);
    }
    #pragma unroll
    for (int off = 32; off >= 1; off >>= 1) {
      mn = fminf(mn, __shfl_xor(mn, off));
      mx = fmaxf(mx, __shfl_xor(mx, off));
    }
    __shared__ float smn[16], smx[16];
    int wv = t >> 6;
    if ((t & 63) == 0) { smn[wv] = mn; smx[wv] = mx; }
    __syncthreads();
    if (t == 0) {
      #pragma unroll
      for (int i = 1; i < 16; ++i) { mn = fminf(mn, smn[i]); mx = fmaxf(mx, smx[i]); }
      gmm[2*m] = mn; gmm[2*m + 1] = mx;
    }
    return;
  }
  // block 12: exclusive scan of 5000 line-padded counts
  __shared__ int part[1024];
  int base = t * 5;
  int v[5]; int sum = 0;
  #pragma unroll
  for (int j = 0; j < 5; ++j) {
    v[j] = (base + j < NBSEG) ? cnt[(base + j) * CNT_STRIDE] : 0;
    sum += v[j];
  }
  part[t] = sum;
  __syncthreads();
  #pragma unroll
  for (int d = 1; d < 1024; d <<= 1) {
    int xv = (t >= d) ? part[t - d] : 0;
    __syncthreads();
    part[t] += xv;
    __syncthreads();
  }
  int run = (t > 0) ? part[t - 1] : 0;   // exclusive
  #pragma unroll
  for (int j = 0; j < 5; ++j) {
    int i = base + j;
    if (i <= NBSEG) start[i] = run;
    run += v[j];
  }
}

// Pass 2: read bf16 grad planes + packed rank/color COALESCED, quantize
// (mul form, params from gmm in-block), pack 16B record, atomic-free scatter.
__global__ __launch_bounds__(256) void k_bin(const int* __restrict__ reg,
                                             const unsigned* __restrict__ rkcp,
                                             const int* __restrict__ start,
                                             const float* __restrict__ gmm,
                                             const uint2* __restrict__ grad2,
                                             uint4* __restrict__ rec) {
  __shared__ float params[48];
  if (threadIdx.x < 24) {
    int t = threadIdx.x;
    int c = t / 8, k = t % 8;
    int b = (k < 4) ? (2*c + (k & 1)) : (6 + 2*c + (k & 1));
    bool pos = ((k >> 1) & 1) == 0;
    float mn = gmm[2*b], mx = gmm[2*b + 1];
    float hmin, hmax;
    if (pos) { hmin = fmaxf(mn, 0.0f); hmax = fmaxf(mx, 0.0f); }
    else     { hmin = fminf(mn, 0.0f); hmax = fminf(mx, 0.0f); }
    params[2*t]     = hmin;
    params[2*t + 1] = 9.0f / (hmax - hmin);
  }
  __syncthreads();

  int p = blockIdx.x * 256 + threadIdx.x;
  int s = reg[p];
  if ((unsigned)s >= (unsigned)NBSEG) return;

  unsigned rc = rkcp[p];
  unsigned cp = rc & 0x3FFFu;
  unsigned rank = rc >> 14;

  unsigned q[24];
  #pragma unroll
  for (int c = 0; c < 3; ++c) {
    uint2 g = grad2[(long)c * NPIX + p];
    float gv[2] = { bf16f(g.x & 0xFFFFu), __uint_as_float(g.x & 0xFFFF0000u) };
    float rv[2] = { bf16f(g.y & 0xFFFFu), __uint_as_float(g.y & 0xFFFF0000u) };
    #pragma unroll
    for (int d = 0; d < 2; ++d) {
      {
        int m = c*8 + d;
        float v = fmaxf(gv[d], 0.0f);
        int qq = (int)((v - params[2*m]) * params[2*m + 1]);
        q[m] = (unsigned)min(max(qq, 0), 9);
      }
      {
        int m = c*8 + 2 + d;
        float v = fminf(gv[d], 0.0f);
        int qq = (int)((v - params[2*m]) * params[2*m + 1]);
        q[m] = (unsigned)min(max(qq, 0), 9);
      }
      {
        int m = c*8 + 4 + d;
        float v = fmaxf(rv[d], 0.0f);
        int qq = (int)((v - params[2*m]) * params[2*m + 1]);
        q[m] = (unsigned)min(max(qq, 0), 9);
      }
      {
        int m = c*8 + 6 + d;
        float v = fminf(rv[d], 0.0f);
        int qq = (int)((v - params[2*m]) * params[2*m + 1]);
        q[m] = (unsigned)min(max(qq, 0), 9);
      }
    }
  }

  unsigned trip[8];
  #pragma unroll
  for (int j = 0; j < 8; ++j)
    trip[j] = q[3*j] + 10u*q[3*j + 1] + 100u*q[3*j + 2];

  uint4 r;
  r.x = (unsigned)p | (trip[0] << 20);
  r.y = trip[1] | (trip[2] << 10) | (trip[3] << 20);
  r.z = trip[4] | (trip[5] << 10) | (trip[6] << 20);
  r.w = trip[7] | (cp << 10);

  rec[start[s] + rank] = r;   // atomic-free scatter
}

// One block per segment, 2 records/lane per pass (512/block): ballot sweep
// counts 128 records per wave-pass (bcnt+accumulate amortized over 2 ballots),
// and waves whose 128-record range is empty SKIP the sweep (uniform branch).
__global__ __launch_bounds__(256) void k_accum(const uint4* __restrict__ rec,
                                               const int* __restrict__ start,
                                               float* __restrict__ out) {
  __shared__ unsigned hist[316];
  __shared__ int bb[4];
  int tid = threadIdx.x;
  int lane = tid & 63;
  int wv = tid >> 6;

  for (int i = tid; i < 316; i += 256) hist[i] = 0;
  if (tid == 0) { bb[0] = INT_MAX; bb[1] = INT_MAX; bb[2] = INT_MIN; bb[3] = INT_MIN; }
  __syncthreads();

  int s = blockIdx.x;
  int beg = start[s], end = start[s + 1];
  int n = end - beg;

  unsigned acc[5] = {0, 0, 0, 0, 0};   // lane-sliced: acc[j] counts bin (64*j + lane)
  int xmn = INT_MAX, ymn = INT_MAX, xmx = INT_MIN, ymx = INT_MIN;

  for (int base2 = beg; base2 < end; base2 += 512) {
    if (base2 + 128 * wv >= end) continue;   // wave-uniform skip: no records for this wave
    int ia = base2 + 2 * tid;
    int ib = ia + 1;
    bool aa = ia < end, ab = ib < end;
    uint4 ra = rec[aa ? ia : beg];
    uint4 rb = rec[ab ? ib : beg];
    unsigned inva = aa ? 0u : 0xFFu;
    unsigned invb = ab ? 0u : 0xFFu;

    unsigned tra[8], trb[8];
    tra[0] = ra.x >> 20;
    tra[1] = ra.y & 0x3FFu; tra[2] = (ra.y >> 10) & 0x3FFu; tra[3] = ra.y >> 20;
    tra[4] = ra.z & 0x3FFu; tra[5] = (ra.z >> 10) & 0x3FFu; tra[6] = ra.z >> 20;
    tra[7] = ra.w & 0x3FFu;
    trb[0] = rb.x >> 20;
    trb[1] = rb.y & 0x3FFu; trb[2] = (rb.y >> 10) & 0x3FFu; trb[3] = rb.y >> 20;
    trb[4] = rb.z & 0x3FFu; trb[5] = (rb.z >> 10) & 0x3FFu; trb[6] = rb.z >> 20;
    trb[7] = rb.w & 0x3FFu;
    unsigned cpa = ra.w >> 10, cpb = rb.w >> 10;

    if (aa) {
      unsigned p = ra.x & 0xFFFFFu;
      int x = (int)(p & 1023u), y = (int)(p >> 10);
      xmn = min(xmn, x); ymn = min(ymn, y);
      xmx = max(xmx, x); ymx = max(ymx, y);
    }
    if (ab) {
      unsigned p = rb.x & 0xFFFFFu;
      int x = (int)(p & 1023u), y = (int)(p >> 10);
      xmn = min(xmn, x); ymn = min(ymn, y);
      xmx = max(xmx, x); ymx = max(ymx, y);
    }

    // tex: per packed triple j, extract 3 map bins for both records, 30 dual-ballots
    #pragma unroll
    for (int j = 0; j < 8; ++j) {
      unsigned ta = tra[j], tb = trb[j];
      unsigned qa2 = ta / 100u; unsigned rra = ta - 100u*qa2;
      unsigned qa1 = rra / 10u; unsigned qa0 = (rra - 10u*qa1) | inva;
      qa1 |= inva; qa2 |= inva;
      unsigned qb2 = tb / 100u; unsigned rrb = tb - 100u*qb2;
      unsigned qb1 = rrb / 10u; unsigned qb0 = (rrb - 10u*qb1) | invb;
      qb1 |= invb; qb2 |= invb;
      unsigned qa[3] = { qa0, qa1, qa2 };
      unsigned qb[3] = { qb0, qb1, qb2 };
      #pragma unroll
      for (int kk = 0; kk < 3; ++kk) {
        #pragma unroll
        for (int b = 0; b < 10; ++b) {
          unsigned cnt2 = (unsigned)__popcll(__ballot(qa[kk] == (unsigned)b))
                        + (unsigned)__popcll(__ballot(qb[kk] == (unsigned)b));
          int idx = (3*j + kk) * 10 + b;
          acc[idx >> 6] += (lane == (idx & 63)) ? cnt2 : 0u;
        }
      }
    }
    // color: 3 channels x 25 bins, dual-ballots
    unsigned ca0 = (cpa % 25u) | inva; unsigned rema = cpa / 25u;
    unsigned ca1 = (rema % 25u) | inva; unsigned ca2 = (rema / 25u) | inva;
    unsigned cb0 = (cpb % 25u) | invb; unsigned remb = cpb / 25u;
    unsigned cb1 = (remb % 25u) | invb; unsigned cb2 = (remb / 25u) | invb;
    unsigned qca[3] = { ca0, ca1, ca2 };
    unsigned qcb[3] = { cb0, cb1, cb2 };
    #pragma unroll
    for (int cm = 0; cm < 3; ++cm) {
      #pragma unroll
      for (int b = 0; b < 25; ++b) {
        unsigned cnt2 = (unsigned)__popcll(__ballot(qca[cm] == (unsigned)b))
                      + (unsigned)__popcll(__ballot(qcb[cm] == (unsigned)b));
        int idx = 240 + cm * 25 + b;
        acc[idx >> 6] += (lane == (idx & 63)) ? cnt2 : 0u;
      }
    }
  }

  // flush lane-sliced counters (5 LDS atomics per wave)
  #pragma unroll
  for (int j = 0; j < 5; ++j) {
    int idx = j * 64 + lane;
    if (idx < 315 && acc[j]) atomicAdd(&hist[idx], acc[j]);
  }

  // bbox: wave shuffle-reduce, then one LDS atomic set per wave
  #pragma unroll
  for (int off = 32; off >= 1; off >>= 1) {
    xmn = min(xmn, __shfl_xor(xmn, off));
    ymn = min(ymn, __shfl_xor(ymn, off));
    xmx = max(xmx, __shfl_xor(xmx, off));
    ymx = max(ymx, __shfl_xor(ymx, off));
  }
  if (lane == 0) {
    atomicMin(&bb[0], xmn); atomicMin(&bb[1], ymn);
    atomicMax(&bb[2], xmx); atomicMax(&bb[3], ymx);
  }
  __syncthreads();

  if (tid == 0) {
    out[4*s + 0] = (float)bb[0];
    out[4*s + 1] = (float)bb[1];
    out[4*s + 2] = (float)(bb[2] - bb[0]);
    out[4*s + 3] = (float)(bb[3] - bb[1]);
    out[OUT_SIZE_OFF + s] = (float)n;
  }
  bool ok = n > 0;
  float cden = 3.0f * (float)n, tden = 24.0f * (float)n;
  for (int i = tid; i < 240; i += 256)
    out[OUT_TEX_OFF + s*240 + i] = ok ? (float)hist[i] / tden : 0.0f;
  for (int i = tid; i < 75; i += 256)
    out[OUT_COLOR_OFF + s*75 + i] = ok ? (float)hist[240 + i] / cden : 0.0f;
}

// ---------------- launch ----------------

extern "C" void kernel_launch(void* const* d_in, const int* in_sizes, int n_in,
                              void* d_out, int out_size, void* d_ws, size_t ws_size,
                              hipStream_t stream) {
  const float* img = (const float*)d_in[0];
  const int*   reg = (const int*)d_in[1];
  float* out = (float*)d_out;

  char* ws = (char*)d_ws;
  size_t off = 0;
  uint2*    grad2 = (uint2*)(ws + off);    off += (size_t)3 * NPIX * 8;       off = (off + 255) & ~(size_t)255;
  uint4*    rec   = (uint4*)(ws + off);    off += (size_t)(NPIX + 512) * 16;  off = (off + 255) & ~(size_t)255;
  unsigned* rkcp  = (unsigned*)(ws + off); off += (size_t)NPIX * 4;           off = (off + 255) & ~(size_t)255;
  int*      cnt   = (int*)(ws + off);      off += (size_t)5008 * CNT_STRIDE * 4;
  int*      start = (int*)(ws + off);      off += 5008 * 4;
  float*    gmm   = (float*)(ws + off);    off += 32 * 4;                     off = (off + 255) & ~(size_t)255;
  float*    pmin  = (float*)(ws + off);    off += (size_t)12 * NBLK_MM * 4;
  float*    pmax  = (float*)(ws + off);    off += (size_t)12 * NBLK_MM * 4;
  (void)ws_size; (void)in_sizes; (void)n_in; (void)out_size;

  double th  = 45.0 * (M_PI / 180.0);
  float cf = (float)cos(th),  sf = (float)sin(th);    // forward +45
  double thb = -45.0 * (M_PI / 180.0);
  float cbk = (float)cos(thb), sbk = (float)sin(thb); // backward -45

  dim3 gMM(WW / TW, HH / TH);   // 16 x 256 = 4096 blocks

  hipMemsetAsync(cnt, 0, (size_t)5008 * CNT_STRIDE * 4, stream);
  k_mm     <<<gMM,       256,  0, stream>>>(img, reg, cnt, rkcp, grad2, pmin, pmax, cbk, sbk, cf, sf);
  k_redscan<<<13,        1024, 0, stream>>>(pmin, pmax, cnt, gmm, start);
  k_bin    <<<NPIX/256,  256,  0, stream>>>(reg, rkcp, start, gmm, grad2, rec);
  k_accum  <<<NBSEG,     256,  0, stream>>>(rec, start, out);
}

// Round 22
// 199.608 us; speedup vs baseline: 1.0977x; 1.0244x over previous
//
#include <hip/hip_runtime.h>
#include <math.h>
#include <float.h>
#include <limits.h>

// ---------------- problem constants (fixed by setup_inputs) ----------------
#define HH 1024
#define WW 1024
#define NPIX (HH*WW)          // 1048576
#define RH 1449               // ceil(1024*sqrt(2))
#define RW 1449
#define NBSEG 5000
#define START 211             // int((rot_bbox_w - 1024)/2) for 45 deg

// k_mm tiling (r17 config — best measured): 64x4 px/block, 1 px/thread, halo 3
#define TW 64
#define TH 4
#define HALO 3
#define TSX (TW + 2*HALO)     // 70
#define TSY (TH + 2*HALO)     // 10
#define TST 71                // padded LDS row stride
#define NBLK_MM 4096          // (1024/64) x (1024/4)

// line-padded segment counters (r20 WIN: k_mm 74->60 us; L2 same-line RMW chains)
#define CNT_STRIDE 16         // ints per counter slot (64 B)

// output layout (floats, concatenated in return order)
#define OUT_XYWH_OFF  0          // 5000*4
#define OUT_SIZE_OFF  20000      // 5000
#define OUT_COLOR_OFF 25000      // 5000*3*25
#define OUT_TEX_OFF   400000     // 5000*3*8*10
#define OUT_TOTAL     1600000

__device__ __forceinline__ unsigned bf16t(float v) { return __float_as_uint(v) >> 16; }
__device__ __forceinline__ float bf16f(unsigned h) { return __uint_as_float(h << 16); }

__device__ __forceinline__ unsigned tripj(const uint4& r, int j) {
  switch (j) {
    case 0: return r.x >> 20;
    case 1: return r.y & 0x3FFu;
    case 2: return (r.y >> 10) & 0x3FFu;
    case 3: return r.y >> 20;
    case 4: return r.z & 0x3FFu;
    case 5: return (r.z >> 10) & 0x3FFu;
    case 6: return r.z >> 20;
    default: return r.w & 0x3FFu;
  }
}

// ---------------- kernels ----------------

// Pass 1 (r17 structure): zero-padded 70x10x3 img tile in LDS; stencil + rot
// taps all LDS. rank and color-bin packed into ONE int plane:
// rkcp[p] = (rank << 14) | cpq.  Counters line-padded (cnt[s*16]).
__global__ __launch_bounds__(256, 6) void k_mm(const float* __restrict__ img,
                                               const int* __restrict__ reg,
                                               int* __restrict__ cnt,
                                               unsigned* __restrict__ rkcp,
                                               uint2* __restrict__ grad2,
                                               float* __restrict__ pmin,
                                               float* __restrict__ pmax,
                                               float cb, float sb, float cf, float sf) {
  __shared__ float tile[3][TSY * TST];
  int tid = threadIdx.x;
  int x0 = blockIdx.x * TW, y0 = blockIdx.y * TH;

  for (int i = tid; i < 3 * TSY * TSX; i += 256) {
    int c = i / (TSY * TSX); int r = i - c * (TSY * TSX);
    int ly = r / TSX, lx = r - ly * TSX;
    int gx = x0 - HALO + lx, gy = y0 - HALO + ly;
    float v = ((unsigned)gx < (unsigned)WW && (unsigned)gy < (unsigned)HH)
              ? img[(long)c * NPIX + (long)gy * WW + gx] : 0.0f;
    tile[c][ly * TST + lx] = v;
  }
  __syncthreads();

  int tx = tid & 63, ty = tid >> 6;
  int x = x0 + tx, y = y0 + ty;
  int p = y * WW + x;
  int s = reg[p];
  int rank = ((unsigned)s < (unsigned)NBSEG) ? atomicAdd(&cnt[s * CNT_STRIDE], 1) : 0;

  float sx, sy;
  {
    #pragma clang fp contract(off)
    float dx = (float)(x + START) - 1024.5f;   // ncx of 2050-grid
    float dy = (float)(y + START) - 1024.5f;
    sx = cb*dx - sb*dy + 724.0f;               // cx of 1449-grid
    sy = sb*dx + cb*dy + 724.0f;
  }
  bool valid2 = (sx >= -0.5f) && (sx <= (float)RW - 0.5f) &&
                (sy >= -0.5f) && (sy <= (float)RH - 0.5f);
  int ix = min(max((int)rintf(sx), 0), RW - 1);
  int iy = min(max((int)rintf(sy), 0), RH - 1);

  float fxc, fyc;
  {
    #pragma clang fp contract(off)
    float ddx = (float)ix - 724.0f;
    float ddy = (float)iy - 724.0f;
    fxc = cf*ddx - sf*ddy + 511.5f;
    fyc = sf*ddx + cf*ddy + 511.5f;
  }

  int lofs[9];
  unsigned okm = 0;
  #pragma unroll
  for (int t = 0; t < 9; ++t) {
    const int dxi = (t % 3) - 1, dyi = (t / 3) - 1;
    int rx = ix + dxi, ry = iy + dyi;
    bool inside = ((unsigned)rx < (unsigned)RW) && ((unsigned)ry < (unsigned)RH);
    float fx = fxc + (cf*(float)dxi - sf*(float)dyi);
    float fy = fyc + (sf*(float)dxi + cf*(float)dyi);
    bool v1 = (fx >= -0.5f) && (fx <= 1023.5f) && (fy >= -0.5f) && (fy <= 1023.5f);
    int jx = min(max((int)rintf(fx), 0), WW - 1);
    int jy = min(max((int)rintf(fy), 0), HH - 1);
    int lx = min(max(jx - x0 + HALO, 0), TSX - 1);
    int ly = min(max(jy - y0 + HALO, 0), TSY - 1);
    lofs[t] = ly * TST + lx;
    okm |= ((unsigned)(inside && v1)) << t;
  }

  float vmn[12], vmx[12];
  int cbase = (ty + HALO) * TST + (tx + HALO);
  unsigned qc[3];
  #pragma unroll
  for (int c = 0; c < 3; ++c) {
    const float* t = &tile[c][0];
    float n00 = t[cbase - TST - 1], n01 = t[cbase - TST], n02 = t[cbase - TST + 1];
    float n10 = t[cbase - 1],       ctr = t[cbase],       n12 = t[cbase + 1];
    float n20 = t[cbase + TST - 1], n21 = t[cbase + TST], n22 = t[cbase + TST + 1];
    float a0 = -3.0f*n00 + 3.0f*n02 + 10.0f*n10 + 10.0f*n12 - 3.0f*n20 + 3.0f*n22;
    float a1 = -3.0f*n00 + 10.0f*n01 - 3.0f*n02 + 3.0f*n20 + 10.0f*n21 + 3.0f*n22;

    float m0 = (okm & 1u)   ? t[lofs[0]] : 0.0f;
    float m1 = (okm & 2u)   ? t[lofs[1]] : 0.0f;
    float m2 = (okm & 4u)   ? t[lofs[2]] : 0.0f;
    float m3 = (okm & 8u)   ? t[lofs[3]] : 0.0f;
    float m5 = (okm & 32u)  ? t[lofs[5]] : 0.0f;
    float m6 = (okm & 64u)  ? t[lofs[6]] : 0.0f;
    float m7 = (okm & 128u) ? t[lofs[7]] : 0.0f;
    float m8 = (okm & 256u) ? t[lofs[8]] : 0.0f;
    float r0 = -3.0f*m0 + 3.0f*m2 + 10.0f*m3 + 10.0f*m5 - 3.0f*m6 + 3.0f*m8;
    float r1 = -3.0f*m0 + 10.0f*m1 - 3.0f*m2 + 3.0f*m6 + 10.0f*m7 + 3.0f*m8;
    float b0 = valid2 ? r0 : 0.0f;
    float b1 = valid2 ? r1 : 0.0f;

    unsigned ua0 = bf16t(a0), ua1 = bf16t(a1), ub0 = bf16t(b0), ub1 = bf16t(b1);
    float a0r = bf16f(ua0), a1r = bf16f(ua1), b0r = bf16f(ub0), b1r = bf16f(ub1);

    grad2[(long)c * NPIX + p] = make_uint2(ua0 | (ua1 << 16), ub0 | (ub1 << 16));

    int cc = (int)(ctr * 24.0f);   // (img*(cb-1)).astype(int32)
    qc[c] = (unsigned)min(max(cc, 0), 24);

    vmn[2*c]     = a0r; vmx[2*c]     = a0r;
    vmn[2*c + 1] = a1r; vmx[2*c + 1] = a1r;
    vmn[6 + 2*c]     = b0r; vmx[6 + 2*c]     = b0r;
    vmn[6 + 2*c + 1] = b1r; vmx[6 + 2*c + 1] = b1r;
  }
  rkcp[p] = ((unsigned)rank << 14) | (qc[0] + 25u*qc[1] + 625u*qc[2]);

  #pragma unroll
  for (int off = 32; off >= 1; off >>= 1) {
    #pragma unroll
    for (int m = 0; m < 12; ++m) {
      vmn[m] = fminf(vmn[m], __shfl_xor(vmn[m], off));
      vmx[m] = fmaxf(vmx[m], __shfl_xor(vmx[m], off));
    }
  }
  __syncthreads();
  __shared__ float smn[12][4], smx[12][4];
  int wv = tid >> 6;
  if ((tid & 63) == 0) {
    #pragma unroll
    for (int m = 0; m < 12; ++m) { smn[m][wv] = vmn[m]; smx[m][wv] = vmx[m]; }
  }
  __syncthreads();
  if (tid < 12) {
    int m = tid;
    float mn = fminf(fminf(smn[m][0], smn[m][1]), fminf(smn[m][2], smn[m][3]));
    float mx = fmaxf(fmaxf(smx[m][0], smx[m][1]), fmaxf(smx[m][2], smx[m][3]));
    int fb = blockIdx.y * gridDim.x + blockIdx.x;
    pmin[m * NBLK_MM + fb] = mn;
    pmax[m * NBLK_MM + fb] = mx;
  }
}

// Fused: blocks 0..11 reduce one map's partials -> gmm; block 12 prefix-scans counts.
__global__ __launch_bounds__(1024) void k_redscan(const float* __restrict__ pmin,
                                                  const float* __restrict__ pmax,
                                                  const int* __restrict__ cnt,
                                                  float* __restrict__ gmm,
                                                  int* __restrict__ start) {
  int t = threadIdx.x;
  if (blockIdx.x < 12) {
    int m = blockIdx.x;
    float mn = FLT_MAX, mx = -FLT_MAX;
    #pragma unroll
    for (int j = 0; j < 4; ++j) {
      mn = fminf(mn, pmin[m * NBLK_MM + t + j * 1024]);
      mx = fmaxf(mx, pmax[m * NBLK_MM + t + j * 1024]);
    }
    #pragma unroll
    for (int off = 32; off >= 1; off >>= 1) {
      mn = fminf(mn, __shfl_xor(mn, off));
      mx = fmaxf(mx, __shfl_xor(mx, off));
    }
    __shared__ float smn[16], smx[16];
    int wv = t >> 6;
    if ((t & 63) == 0) { smn[wv] = mn; smx[wv] = mx; }
    __syncthreads();
    if (t == 0) {
      #pragma unroll
      for (int i = 1; i < 16; ++i) { mn = fminf(mn, smn[i]); mx = fmaxf(mx, smx[i]); }
      gmm[2*m] = mn; gmm[2*m + 1] = mx;
    }
    return;
  }
  // block 12: exclusive scan of 5000 line-padded counts
  __shared__ int part[1024];
  int base = t * 5;
  int v[5]; int sum = 0;
  #pragma unroll
  for (int j = 0; j < 5; ++j) {
    v[j] = (base + j < NBSEG) ? cnt[(base + j) * CNT_STRIDE] : 0;
    sum += v[j];
  }
  part[t] = sum;
  __syncthreads();
  #pragma unroll
  for (int d = 1; d < 1024; d <<= 1) {
    int xv = (t >= d) ? part[t - d] : 0;
    __syncthreads();
    part[t] += xv;
    __syncthreads();
  }
  int run = (t > 0) ? part[t - 1] : 0;   // exclusive
  #pragma unroll
  for (int j = 0; j < 5; ++j) {
    int i = base + j;
    if (i <= NBSEG) start[i] = run;
    run += v[j];
  }
}

// Pass 2: read bf16 grad planes + packed rank/color COALESCED, quantize
// (mul form, params from gmm in-block), pack 16B record, atomic-free scatter.
__global__ __launch_bounds__(256) void k_bin(const int* __restrict__ reg,
                                             const unsigned* __restrict__ rkcp,
                                             const int* __restrict__ start,
                                             const float* __restrict__ gmm,
                                             const uint2* __restrict__ grad2,
                                             uint4* __restrict__ rec) {
  __shared__ float params[48];
  if (threadIdx.x < 24) {
    int t = threadIdx.x;
    int c = t / 8, k = t % 8;
    int b = (k < 4) ? (2*c + (k & 1)) : (6 + 2*c + (k & 1));
    bool pos = ((k >> 1) & 1) == 0;
    float mn = gmm[2*b], mx = gmm[2*b + 1];
    float hmin, hmax;
    if (pos) { hmin = fmaxf(mn, 0.0f); hmax = fmaxf(mx, 0.0f); }
    else     { hmin = fminf(mn, 0.0f); hmax = fminf(mx, 0.0f); }
    params[2*t]     = hmin;
    params[2*t + 1] = 9.0f / (hmax - hmin);
  }
  __syncthreads();

  int p = blockIdx.x * 256 + threadIdx.x;
  int s = reg[p];
  if ((unsigned)s >= (unsigned)NBSEG) return;

  unsigned rc = rkcp[p];
  unsigned cp = rc & 0x3FFFu;
  unsigned rank = rc >> 14;

  unsigned q[24];
  #pragma unroll
  for (int c = 0; c < 3; ++c) {
    uint2 g = grad2[(long)c * NPIX + p];
    float gv[2] = { bf16f(g.x & 0xFFFFu), __uint_as_float(g.x & 0xFFFF0000u) };
    float rv[2] = { bf16f(g.y & 0xFFFFu), __uint_as_float(g.y & 0xFFFF0000u) };
    #pragma unroll
    for (int d = 0; d < 2; ++d) {
      {
        int m = c*8 + d;
        float v = fmaxf(gv[d], 0.0f);
        int qq = (int)((v - params[2*m]) * params[2*m + 1]);
        q[m] = (unsigned)min(max(qq, 0), 9);
      }
      {
        int m = c*8 + 2 + d;
        float v = fminf(gv[d], 0.0f);
        int qq = (int)((v - params[2*m]) * params[2*m + 1]);
        q[m] = (unsigned)min(max(qq, 0), 9);
      }
      {
        int m = c*8 + 4 + d;
        float v = fmaxf(rv[d], 0.0f);
        int qq = (int)((v - params[2*m]) * params[2*m + 1]);
        q[m] = (unsigned)min(max(qq, 0), 9);
      }
      {
        int m = c*8 + 6 + d;
        float v = fminf(rv[d], 0.0f);
        int qq = (int)((v - params[2*m]) * params[2*m + 1]);
        q[m] = (unsigned)min(max(qq, 0), 9);
      }
    }
  }

  unsigned trip[8];
  #pragma unroll
  for (int j = 0; j < 8; ++j)
    trip[j] = q[3*j] + 10u*q[3*j + 1] + 100u*q[3*j + 2];

  uint4 r;
  r.x = (unsigned)p | (trip[0] << 20);
  r.y = trip[1] | (trip[2] << 10) | (trip[3] << 20);
  r.z = trip[4] | (trip[5] << 10) | (trip[6] << 20);
  r.w = trip[7] | (cp << 10);

  rec[start[s] + rank] = r;   // atomic-free scatter
}

// One WAVE per segment (64 threads, no LDS, no barriers): 4 records/lane per
// pass (256/block) — quad-ballot sweep, lane-sliced register histogram written
// straight to out. r21 lesson: 256-thread blocks left 2 waves idle and paid
// LDS/barrier overhead; the histogram fits entirely in 5 regs/lane.
__global__ __launch_bounds__(64) void k_accum(const uint4* __restrict__ rec,
                                              const int* __restrict__ start,
                                              float* __restrict__ out) {
  int lane = threadIdx.x;
  int s = blockIdx.x;
  int beg = start[s], end = start[s + 1];
  int n = end - beg;

  unsigned acc[5] = {0, 0, 0, 0, 0};   // lane-sliced: acc[j] counts bin (64*j + lane)
  int xmn = INT_MAX, ymn = INT_MAX, xmx = INT_MIN, ymx = INT_MIN;

  for (int base = beg; base < end; base += 256) {
    uint4 rr[4]; unsigned inv[4];
    #pragma unroll
    for (int r = 0; r < 4; ++r) {
      int i = base + lane + 64 * r;   // coalesced per r
      bool a = i < end;
      rr[r] = rec[a ? i : beg];
      inv[r] = a ? 0u : 0xFFu;
      if (a) {
        unsigned p = rr[r].x & 0xFFFFFu;
        int x = (int)(p & 1023u), y = (int)(p >> 10);
        xmn = min(xmn, x); ymn = min(ymn, y);
        xmx = max(xmx, x); ymx = max(ymx, y);
      }
    }

    // tex: 8 packed triples -> 24 maps x 10 bins, quad-ballot per bin
    #pragma unroll
    for (int j = 0; j < 8; ++j) {
      unsigned q0[4], q1[4], q2[4];
      #pragma unroll
      for (int r = 0; r < 4; ++r) {
        unsigned t = tripj(rr[r], j);
        unsigned a2 = t / 100u; unsigned rm = t - 100u * a2;
        unsigned a1 = rm / 10u; unsigned a0 = rm - 10u * a1;
        q0[r] = a0 | inv[r]; q1[r] = a1 | inv[r]; q2[r] = a2 | inv[r];
      }
      #pragma unroll
      for (int kk = 0; kk < 3; ++kk) {
        const unsigned* q = (kk == 0) ? q0 : (kk == 1) ? q1 : q2;
        #pragma unroll
        for (int b = 0; b < 10; ++b) {
          unsigned cnt = (unsigned)__popcll(__ballot(q[0] == (unsigned)b))
                       + (unsigned)__popcll(__ballot(q[1] == (unsigned)b))
                       + (unsigned)__popcll(__ballot(q[2] == (unsigned)b))
                       + (unsigned)__popcll(__ballot(q[3] == (unsigned)b));
          int idx = (3*j + kk) * 10 + b;
          acc[idx >> 6] += (lane == (idx & 63)) ? cnt : 0u;
        }
      }
    }
    // color: 3 channels x 25 bins, quad-ballot
    unsigned c0[4], c1[4], c2[4];
    #pragma unroll
    for (int r = 0; r < 4; ++r) {
      unsigned cp = rr[r].w >> 10;
      c0[r] = (cp % 25u) | inv[r];
      unsigned rem = cp / 25u;
      c1[r] = (rem % 25u) | inv[r];
      c2[r] = (rem / 25u) | inv[r];
    }
    #pragma unroll
    for (int cm = 0; cm < 3; ++cm) {
      const unsigned* q = (cm == 0) ? c0 : (cm == 1) ? c1 : c2;
      #pragma unroll
      for (int b = 0; b < 25; ++b) {
        unsigned cnt = (unsigned)__popcll(__ballot(q[0] == (unsigned)b))
                     + (unsigned)__popcll(__ballot(q[1] == (unsigned)b))
                     + (unsigned)__popcll(__ballot(q[2] == (unsigned)b))
                     + (unsigned)__popcll(__ballot(q[3] == (unsigned)b));
        int idx = 240 + cm * 25 + b;
        acc[idx >> 6] += (lane == (idx & 63)) ? cnt : 0u;
      }
    }
  }

  // bbox: wave shuffle-reduce; lane 0 writes
  #pragma unroll
  for (int off = 32; off >= 1; off >>= 1) {
    xmn = min(xmn, __shfl_xor(xmn, off));
    ymn = min(ymn, __shfl_xor(ymn, off));
    xmx = max(xmx, __shfl_xor(xmx, off));
    ymx = max(ymx, __shfl_xor(ymx, off));
  }
  if (lane == 0) {
    out[4*s + 0] = (float)xmn;
    out[4*s + 1] = (float)ymn;
    out[4*s + 2] = (float)(xmx - xmn);
    out[4*s + 3] = (float)(ymx - ymn);
    out[OUT_SIZE_OFF + s] = (float)n;
  }

  bool ok = n > 0;
  float cden = 3.0f * (float)n, tden = 24.0f * (float)n;
  #pragma unroll
  for (int j = 0; j < 5; ++j) {
    int idx = j * 64 + lane;
    if (idx < 240)      out[OUT_TEX_OFF + s*240 + idx]           = ok ? (float)acc[j] / tden : 0.0f;
    else if (idx < 315) out[OUT_COLOR_OFF + s*75 + (idx - 240)]  = ok ? (float)acc[j] / cden : 0.0f;
  }
}

// ---------------- launch ----------------

extern "C" void kernel_launch(void* const* d_in, const int* in_sizes, int n_in,
                              void* d_out, int out_size, void* d_ws, size_t ws_size,
                              hipStream_t stream) {
  const float* img = (const float*)d_in[0];
  const int*   reg = (const int*)d_in[1];
  float* out = (float*)d_out;

  char* ws = (char*)d_ws;
  size_t off = 0;
  uint2*    grad2 = (uint2*)(ws + off);    off += (size_t)3 * NPIX * 8;       off = (off + 255) & ~(size_t)255;
  uint4*    rec   = (uint4*)(ws + off);    off += (size_t)(NPIX + 512) * 16;  off = (off + 255) & ~(size_t)255;
  unsigned* rkcp  = (unsigned*)(ws + off); off += (size_t)NPIX * 4;           off = (off + 255) & ~(size_t)255;
  int*      cnt   = (int*)(ws + off);      off += (size_t)5008 * CNT_STRIDE * 4;
  int*      start = (int*)(ws + off);      off += 5008 * 4;
  float*    gmm   = (float*)(ws + off);    off += 32 * 4;                     off = (off + 255) & ~(size_t)255;
  float*    pmin  = (float*)(ws + off);    off += (size_t)12 * NBLK_MM * 4;
  float*    pmax  = (float*)(ws + off);    off += (size_t)12 * NBLK_MM * 4;
  (void)ws_size; (void)in_sizes; (void)n_in; (void)out_size;

  double th  = 45.0 * (M_PI / 180.0);
  float cf = (float)cos(th),  sf = (float)sin(th);    // forward +45
  double thb = -45.0 * (M_PI / 180.0);
  float cbk = (float)cos(thb), sbk = (float)sin(thb); // backward -45

  dim3 gMM(WW / TW, HH / TH);   // 16 x 256 = 4096 blocks

  hipMemsetAsync(cnt, 0, (size_t)5008 * CNT_STRIDE * 4, stream);
  k_mm     <<<gMM,       256,  0, stream>>>(img, reg, cnt, rkcp, grad2, pmin, pmax, cbk, sbk, cf, sf);
  k_redscan<<<13,        1024, 0, stream>>>(pmin, pmax, cnt, gmm, start);
  k_bin    <<<NPIX/256,  256,  0, stream>>>(reg, rkcp, start, gmm, grad2, rec);
  k_accum  <<<NBSEG,     64,   0, stream>>>(rec, start, out);
}

// Round 23
// 199.507 us; speedup vs baseline: 1.0982x; 1.0005x over previous
//
#include <hip/hip_runtime.h>
#include <math.h>
#include <float.h>
#include <limits.h>

// ---------------- problem constants (fixed by setup_inputs) ----------------
#define HH 1024
#define WW 1024
#define NPIX (HH*WW)          // 1048576
#define RH 1449               // ceil(1024*sqrt(2))
#define RW 1449
#define NBSEG 5000
#define START 211             // int((rot_bbox_w - 1024)/2) for 45 deg

// k_mm tiling (r17 config — best measured): 64x4 px/block, 1 px/thread, halo 3
#define TW 64
#define TH 4
#define HALO 3
#define TSX (TW + 2*HALO)     // 70
#define TSY (TH + 2*HALO)     // 10
#define TST 71                // padded LDS row stride
#define NBLK_MM 4096          // (1024/64) x (1024/4)

// line-padded segment counters (r20 WIN: k_mm 74->60 us; L2 same-line RMW chains)
#define CNT_STRIDE 16         // ints per counter slot (64 B)

// output layout (floats, concatenated in return order)
#define OUT_XYWH_OFF  0          // 5000*4
#define OUT_SIZE_OFF  20000      // 5000
#define OUT_COLOR_OFF 25000      // 5000*3*25
#define OUT_TEX_OFF   400000     // 5000*3*8*10
#define OUT_TOTAL     1600000

__device__ __forceinline__ unsigned bf16t(float v) { return __float_as_uint(v) >> 16; }
__device__ __forceinline__ float bf16f(unsigned h) { return __uint_as_float(h << 16); }

__device__ __forceinline__ unsigned tripj(const uint4& r, int j) {
  switch (j) {
    case 0: return r.x >> 20;
    case 1: return r.y & 0x3FFu;
    case 2: return (r.y >> 10) & 0x3FFu;
    case 3: return r.y >> 20;
    case 4: return r.z & 0x3FFu;
    case 5: return (r.z >> 10) & 0x3FFu;
    case 6: return r.z >> 20;
    default: return r.w & 0x3FFu;
  }
}

// ---------------- kernels ----------------

// Pass 1 (r17 structure): zero-padded 70x10x3 img tile in LDS; stencil + rot
// taps all LDS. rank and color-bin packed into ONE int plane:
// rkcp[p] = (rank << 14) | cpq.  Counters line-padded (cnt[s*16]).
// r23: launch_bounds (256,8) — (256,6) was capping occupancy at 62% (r22);
// LDS 9.2KB x 8 = 74KB < 160KB, VGPR 28 -> full 32 waves/CU now possible.
__global__ __launch_bounds__(256, 8) void k_mm(const float* __restrict__ img,
                                               const int* __restrict__ reg,
                                               int* __restrict__ cnt,
                                               unsigned* __restrict__ rkcp,
                                               uint2* __restrict__ grad2,
                                               float* __restrict__ pmin,
                                               float* __restrict__ pmax,
                                               float cb, float sb, float cf, float sf) {
  __shared__ float tile[3][TSY * TST];
  int tid = threadIdx.x;
  int x0 = blockIdx.x * TW, y0 = blockIdx.y * TH;

  for (int i = tid; i < 3 * TSY * TSX; i += 256) {
    int c = i / (TSY * TSX); int r = i - c * (TSY * TSX);
    int ly = r / TSX, lx = r - ly * TSX;
    int gx = x0 - HALO + lx, gy = y0 - HALO + ly;
    float v = ((unsigned)gx < (unsigned)WW && (unsigned)gy < (unsigned)HH)
              ? img[(long)c * NPIX + (long)gy * WW + gx] : 0.0f;
    tile[c][ly * TST + lx] = v;
  }
  __syncthreads();

  int tx = tid & 63, ty = tid >> 6;
  int x = x0 + tx, y = y0 + ty;
  int p = y * WW + x;
  int s = reg[p];
  int rank = ((unsigned)s < (unsigned)NBSEG) ? atomicAdd(&cnt[s * CNT_STRIDE], 1) : 0;

  float sx, sy;
  {
    #pragma clang fp contract(off)
    float dx = (float)(x + START) - 1024.5f;   // ncx of 2050-grid
    float dy = (float)(y + START) - 1024.5f;
    sx = cb*dx - sb*dy + 724.0f;               // cx of 1449-grid
    sy = sb*dx + cb*dy + 724.0f;
  }
  bool valid2 = (sx >= -0.5f) && (sx <= (float)RW - 0.5f) &&
                (sy >= -0.5f) && (sy <= (float)RH - 0.5f);
  int ix = min(max((int)rintf(sx), 0), RW - 1);
  int iy = min(max((int)rintf(sy), 0), RH - 1);

  float fxc, fyc;
  {
    #pragma clang fp contract(off)
    float ddx = (float)ix - 724.0f;
    float ddy = (float)iy - 724.0f;
    fxc = cf*ddx - sf*ddy + 511.5f;
    fyc = sf*ddx + cf*ddy + 511.5f;
  }

  int lofs[9];
  unsigned okm = 0;
  #pragma unroll
  for (int t = 0; t < 9; ++t) {
    const int dxi = (t % 3) - 1, dyi = (t / 3) - 1;
    int rx = ix + dxi, ry = iy + dyi;
    bool inside = ((unsigned)rx < (unsigned)RW) && ((unsigned)ry < (unsigned)RH);
    float fx = fxc + (cf*(float)dxi - sf*(float)dyi);
    float fy = fyc + (sf*(float)dxi + cf*(float)dyi);
    bool v1 = (fx >= -0.5f) && (fx <= 1023.5f) && (fy >= -0.5f) && (fy <= 1023.5f);
    int jx = min(max((int)rintf(fx), 0), WW - 1);
    int jy = min(max((int)rintf(fy), 0), HH - 1);
    int lx = min(max(jx - x0 + HALO, 0), TSX - 1);
    int ly = min(max(jy - y0 + HALO, 0), TSY - 1);
    lofs[t] = ly * TST + lx;
    okm |= ((unsigned)(inside && v1)) << t;
  }

  float vmn[12], vmx[12];
  int cbase = (ty + HALO) * TST + (tx + HALO);
  unsigned qc[3];
  #pragma unroll
  for (int c = 0; c < 3; ++c) {
    const float* t = &tile[c][0];
    float n00 = t[cbase - TST - 1], n01 = t[cbase - TST], n02 = t[cbase - TST + 1];
    float n10 = t[cbase - 1],       ctr = t[cbase],       n12 = t[cbase + 1];
    float n20 = t[cbase + TST - 1], n21 = t[cbase + TST], n22 = t[cbase + TST + 1];
    float a0 = -3.0f*n00 + 3.0f*n02 + 10.0f*n10 + 10.0f*n12 - 3.0f*n20 + 3.0f*n22;
    float a1 = -3.0f*n00 + 10.0f*n01 - 3.0f*n02 + 3.0f*n20 + 10.0f*n21 + 3.0f*n22;

    float m0 = (okm & 1u)   ? t[lofs[0]] : 0.0f;
    float m1 = (okm & 2u)   ? t[lofs[1]] : 0.0f;
    float m2 = (okm & 4u)   ? t[lofs[2]] : 0.0f;
    float m3 = (okm & 8u)   ? t[lofs[3]] : 0.0f;
    float m5 = (okm & 32u)  ? t[lofs[5]] : 0.0f;
    float m6 = (okm & 64u)  ? t[lofs[6]] : 0.0f;
    float m7 = (okm & 128u) ? t[lofs[7]] : 0.0f;
    float m8 = (okm & 256u) ? t[lofs[8]] : 0.0f;
    float r0 = -3.0f*m0 + 3.0f*m2 + 10.0f*m3 + 10.0f*m5 - 3.0f*m6 + 3.0f*m8;
    float r1 = -3.0f*m0 + 10.0f*m1 - 3.0f*m2 + 3.0f*m6 + 10.0f*m7 + 3.0f*m8;
    float b0 = valid2 ? r0 : 0.0f;
    float b1 = valid2 ? r1 : 0.0f;

    unsigned ua0 = bf16t(a0), ua1 = bf16t(a1), ub0 = bf16t(b0), ub1 = bf16t(b1);
    float a0r = bf16f(ua0), a1r = bf16f(ua1), b0r = bf16f(ub0), b1r = bf16f(ub1);

    grad2[(long)c * NPIX + p] = make_uint2(ua0 | (ua1 << 16), ub0 | (ub1 << 16));

    int cc = (int)(ctr * 24.0f);   // (img*(cb-1)).astype(int32)
    qc[c] = (unsigned)min(max(cc, 0), 24);

    vmn[2*c]     = a0r; vmx[2*c]     = a0r;
    vmn[2*c + 1] = a1r; vmx[2*c + 1] = a1r;
    vmn[6 + 2*c]     = b0r; vmx[6 + 2*c]     = b0r;
    vmn[6 + 2*c + 1] = b1r; vmx[6 + 2*c + 1] = b1r;
  }
  rkcp[p] = ((unsigned)rank << 14) | (qc[0] + 25u*qc[1] + 625u*qc[2]);

  #pragma unroll
  for (int off = 32; off >= 1; off >>= 1) {
    #pragma unroll
    for (int m = 0; m < 12; ++m) {
      vmn[m] = fminf(vmn[m], __shfl_xor(vmn[m], off));
      vmx[m] = fmaxf(vmx[m], __shfl_xor(vmx[m], off));
    }
  }
  __syncthreads();
  __shared__ float smn[12][4], smx[12][4];
  int wv = tid >> 6;
  if ((tid & 63) == 0) {
    #pragma unroll
    for (int m = 0; m < 12; ++m) { smn[m][wv] = vmn[m]; smx[m][wv] = vmx[m]; }
  }
  __syncthreads();
  if (tid < 12) {
    int m = tid;
    float mn = fminf(fminf(smn[m][0], smn[m][1]), fminf(smn[m][2], smn[m][3]));
    float mx = fmaxf(fmaxf(smx[m][0], smx[m][1]), fmaxf(smx[m][2], smx[m][3]));
    int fb = blockIdx.y * gridDim.x + blockIdx.x;
    pmin[m * NBLK_MM + fb] = mn;
    pmax[m * NBLK_MM + fb] = mx;
  }
}

// Fused: blocks 0..11 reduce one map's partials -> gmm; block 12 prefix-scans counts.
__global__ __launch_bounds__(1024) void k_redscan(const float* __restrict__ pmin,
                                                  const float* __restrict__ pmax,
                                                  const int* __restrict__ cnt,
                                                  float* __restrict__ gmm,
                                                  int* __restrict__ start) {
  int t = threadIdx.x;
  if (blockIdx.x < 12) {
    int m = blockIdx.x;
    float mn = FLT_MAX, mx = -FLT_MAX;
    #pragma unroll
    for (int j = 0; j < 4; ++j) {
      mn = fminf(mn, pmin[m * NBLK_MM + t + j * 1024]);
      mx = fmaxf(mx, pmax[m * NBLK_MM + t + j * 1024]);
    }
    #pragma unroll
    for (int off = 32; off >= 1; off >>= 1) {
      mn = fminf(mn, __shfl_xor(mn, off));
      mx = fmaxf(mx, __shfl_xor(mx, off));
    }
    __shared__ float smn[16], smx[16];
    int wv = t >> 6;
    if ((t & 63) == 0) { smn[wv] = mn; smx[wv] = mx; }
    __syncthreads();
    if (t == 0) {
      #pragma unroll
      for (int i = 1; i < 16; ++i) { mn = fminf(mn, smn[i]); mx = fmaxf(mx, smx[i]); }
      gmm[2*m] = mn; gmm[2*m + 1] = mx;
    }
    return;
  }
  // block 12: exclusive scan of 5000 line-padded counts
  __shared__ int part[1024];
  int base = t * 5;
  int v[5]; int sum = 0;
  #pragma unroll
  for (int j = 0; j < 5; ++j) {
    v[j] = (base + j < NBSEG) ? cnt[(base + j) * CNT_STRIDE] : 0;
    sum += v[j];
  }
  part[t] = sum;
  __syncthreads();
  #pragma unroll
  for (int d = 1; d < 1024; d <<= 1) {
    int xv = (t >= d) ? part[t - d] : 0;
    __syncthreads();
    part[t] += xv;
    __syncthreads();
  }
  int run = (t > 0) ? part[t - 1] : 0;   // exclusive
  #pragma unroll
  for (int j = 0; j < 5; ++j) {
    int i = base + j;
    if (i <= NBSEG) start[i] = run;
    run += v[j];
  }
}

// Pass 2: read bf16 grad planes + packed rank/color COALESCED, quantize
// (mul form, params from gmm in-block), pack 16B record, atomic-free scatter.
__global__ __launch_bounds__(256) void k_bin(const int* __restrict__ reg,
                                             const unsigned* __restrict__ rkcp,
                                             const int* __restrict__ start,
                                             const float* __restrict__ gmm,
                                             const uint2* __restrict__ grad2,
                                             uint4* __restrict__ rec) {
  __shared__ float params[48];
  if (threadIdx.x < 24) {
    int t = threadIdx.x;
    int c = t / 8, k = t % 8;
    int b = (k < 4) ? (2*c + (k & 1)) : (6 + 2*c + (k & 1));
    bool pos = ((k >> 1) & 1) == 0;
    float mn = gmm[2*b], mx = gmm[2*b + 1];
    float hmin, hmax;
    if (pos) { hmin = fmaxf(mn, 0.0f); hmax = fmaxf(mx, 0.0f); }
    else     { hmin = fminf(mn, 0.0f); hmax = fminf(mx, 0.0f); }
    params[2*t]     = hmin;
    params[2*t + 1] = 9.0f / (hmax - hmin);
  }
  __syncthreads();

  int p = blockIdx.x * 256 + threadIdx.x;
  int s = reg[p];
  if ((unsigned)s >= (unsigned)NBSEG) return;

  unsigned rc = rkcp[p];
  unsigned cp = rc & 0x3FFFu;
  unsigned rank = rc >> 14;

  unsigned q[24];
  #pragma unroll
  for (int c = 0; c < 3; ++c) {
    uint2 g = grad2[(long)c * NPIX + p];
    float gv[2] = { bf16f(g.x & 0xFFFFu), __uint_as_float(g.x & 0xFFFF0000u) };
    float rv[2] = { bf16f(g.y & 0xFFFFu), __uint_as_float(g.y & 0xFFFF0000u) };
    #pragma unroll
    for (int d = 0; d < 2; ++d) {
      {
        int m = c*8 + d;
        float v = fmaxf(gv[d], 0.0f);
        int qq = (int)((v - params[2*m]) * params[2*m + 1]);
        q[m] = (unsigned)min(max(qq, 0), 9);
      }
      {
        int m = c*8 + 2 + d;
        float v = fminf(gv[d], 0.0f);
        int qq = (int)((v - params[2*m]) * params[2*m + 1]);
        q[m] = (unsigned)min(max(qq, 0), 9);
      }
      {
        int m = c*8 + 4 + d;
        float v = fmaxf(rv[d], 0.0f);
        int qq = (int)((v - params[2*m]) * params[2*m + 1]);
        q[m] = (unsigned)min(max(qq, 0), 9);
      }
      {
        int m = c*8 + 6 + d;
        float v = fminf(rv[d], 0.0f);
        int qq = (int)((v - params[2*m]) * params[2*m + 1]);
        q[m] = (unsigned)min(max(qq, 0), 9);
      }
    }
  }

  unsigned trip[8];
  #pragma unroll
  for (int j = 0; j < 8; ++j)
    trip[j] = q[3*j] + 10u*q[3*j + 1] + 100u*q[3*j + 2];

  uint4 r;
  r.x = (unsigned)p | (trip[0] << 20);
  r.y = trip[1] | (trip[2] << 10) | (trip[3] << 20);
  r.z = trip[4] | (trip[5] << 10) | (trip[6] << 20);
  r.w = trip[7] | (cp << 10);

  rec[start[s] + rank] = r;   // atomic-free scatter
}

// One WAVE per segment (64 threads, no LDS, no barriers): 4 records/lane per
// pass (256/block) — quad-ballot sweep, lane-sliced register histogram written
// straight to out.
__global__ __launch_bounds__(64) void k_accum(const uint4* __restrict__ rec,
                                              const int* __restrict__ start,
                                              float* __restrict__ out) {
  int lane = threadIdx.x;
  int s = blockIdx.x;
  int beg = start[s], end = start[s + 1];
  int n = end - beg;

  unsigned acc[5] = {0, 0, 0, 0, 0};   // lane-sliced: acc[j] counts bin (64*j + lane)
  int xmn = INT_MAX, ymn = INT_MAX, xmx = INT_MIN, ymx = INT_MIN;

  for (int base = beg; base < end; base += 256) {
    uint4 rr[4]; unsigned inv[4];
    #pragma unroll
    for (int r = 0; r < 4; ++r) {
      int i = base + lane + 64 * r;   // coalesced per r
      bool a = i < end;
      rr[r] = rec[a ? i : beg];
      inv[r] = a ? 0u : 0xFFu;
      if (a) {
        unsigned p = rr[r].x & 0xFFFFFu;
        int x = (int)(p & 1023u), y = (int)(p >> 10);
        xmn = min(xmn, x); ymn = min(ymn, y);
        xmx = max(xmx, x); ymx = max(ymx, y);
      }
    }

    // tex: 8 packed triples -> 24 maps x 10 bins, quad-ballot per bin
    #pragma unroll
    for (int j = 0; j < 8; ++j) {
      unsigned q0[4], q1[4], q2[4];
      #pragma unroll
      for (int r = 0; r < 4; ++r) {
        unsigned t = tripj(rr[r], j);
        unsigned a2 = t / 100u; unsigned rm = t - 100u * a2;
        unsigned a1 = rm / 10u; unsigned a0 = rm - 10u * a1;
        q0[r] = a0 | inv[r]; q1[r] = a1 | inv[r]; q2[r] = a2 | inv[r];
      }
      #pragma unroll
      for (int kk = 0; kk < 3; ++kk) {
        const unsigned* q = (kk == 0) ? q0 : (kk == 1) ? q1 : q2;
        #pragma unroll
        for (int b = 0; b < 10; ++b) {
          unsigned cnt = (unsigned)__popcll(__ballot(q[0] == (unsigned)b))
                       + (unsigned)__popcll(__ballot(q[1] == (unsigned)b))
                       + (unsigned)__popcll(__ballot(q[2] == (unsigned)b))
                       + (unsigned)__popcll(__ballot(q[3] == (unsigned)b));
          int idx = (3*j + kk) * 10 + b;
          acc[idx >> 6] += (lane == (idx & 63)) ? cnt : 0u;
        }
      }
    }
    // color: 3 channels x 25 bins, quad-ballot
    unsigned c0[4], c1[4], c2[4];
    #pragma unroll
    for (int r = 0; r < 4; ++r) {
      unsigned cp = rr[r].w >> 10;
      c0[r] = (cp % 25u) | inv[r];
      unsigned rem = cp / 25u;
      c1[r] = (rem % 25u) | inv[r];
      c2[r] = (rem / 25u) | inv[r];
    }
    #pragma unroll
    for (int cm = 0; cm < 3; ++cm) {
      const unsigned* q = (cm == 0) ? c0 : (cm == 1) ? c1 : c2;
      #pragma unroll
      for (int b = 0; b < 25; ++b) {
        unsigned cnt = (unsigned)__popcll(__ballot(q[0] == (unsigned)b))
                     + (unsigned)__popcll(__ballot(q[1] == (unsigned)b))
                     + (unsigned)__popcll(__ballot(q[2] == (unsigned)b))
                     + (unsigned)__popcll(__ballot(q[3] == (unsigned)b));
        int idx = 240 + cm * 25 + b;
        acc[idx >> 6] += (lane == (idx & 63)) ? cnt : 0u;
      }
    }
  }

  // bbox: wave shuffle-reduce; lane 0 writes
  #pragma unroll
  for (int off = 32; off >= 1; off >>= 1) {
    xmn = min(xmn, __shfl_xor(xmn, off));
    ymn = min(ymn, __shfl_xor(ymn, off));
    xmx = max(xmx, __shfl_xor(xmx, off));
    ymx = max(ymx, __shfl_xor(ymx, off));
  }
  if (lane == 0) {
    out[4*s + 0] = (float)xmn;
    out[4*s + 1] = (float)ymn;
    out[4*s + 2] = (float)(xmx - xmn);
    out[4*s + 3] = (float)(ymx - ymn);
    out[OUT_SIZE_OFF + s] = (float)n;
  }

  bool ok = n > 0;
  float cden = 3.0f * (float)n, tden = 24.0f * (float)n;
  #pragma unroll
  for (int j = 0; j < 5; ++j) {
    int idx = j * 64 + lane;
    if (idx < 240)      out[OUT_TEX_OFF + s*240 + idx]           = ok ? (float)acc[j] / tden : 0.0f;
    else if (idx < 315) out[OUT_COLOR_OFF + s*75 + (idx - 240)]  = ok ? (float)acc[j] / cden : 0.0f;
  }
}

// ---------------- launch ----------------

extern "C" void kernel_launch(void* const* d_in, const int* in_sizes, int n_in,
                              void* d_out, int out_size, void* d_ws, size_t ws_size,
                              hipStream_t stream) {
  const float* img = (const float*)d_in[0];
  const int*   reg = (const int*)d_in[1];
  float* out = (float*)d_out;

  char* ws = (char*)d_ws;
  size_t off = 0;
  uint2*    grad2 = (uint2*)(ws + off);    off += (size_t)3 * NPIX * 8;       off = (off + 255) & ~(size_t)255;
  uint4*    rec   = (uint4*)(ws + off);    off += (size_t)(NPIX + 512) * 16;  off = (off + 255) & ~(size_t)255;
  unsigned* rkcp  = (unsigned*)(ws + off); off += (size_t)NPIX * 4;           off = (off + 255) & ~(size_t)255;
  int*      cnt   = (int*)(ws + off);      off += (size_t)5008 * CNT_STRIDE * 4;
  int*      start = (int*)(ws + off);      off += 5008 * 4;
  float*    gmm   = (float*)(ws + off);    off += 32 * 4;                     off = (off + 255) & ~(size_t)255;
  float*    pmin  = (float*)(ws + off);    off += (size_t)12 * NBLK_MM * 4;
  float*    pmax  = (float*)(ws + off);    off += (size_t)12 * NBLK_MM * 4;
  (void)ws_size; (void)in_sizes; (void)n_in; (void)out_size;

  double th  = 45.0 * (M_PI / 180.0);
  float cf = (float)cos(th),  sf = (float)sin(th);    // forward +45
  double thb = -45.0 * (M_PI / 180.0);
  float cbk = (float)cos(thb), sbk = (float)sin(thb); // backward -45

  dim3 gMM(WW / TW, HH / TH);   // 16 x 256 = 4096 blocks

  hipMemsetAsync(cnt, 0, (size_t)5008 * CNT_STRIDE * 4, stream);
  k_mm     <<<gMM,       256,  0, stream>>>(img, reg, cnt, rkcp, grad2, pmin, pmax, cbk, sbk, cf, sf);
  k_redscan<<<13,        1024, 0, stream>>>(pmin, pmax, cnt, gmm, start);
  k_bin    <<<NPIX/256,  256,  0, stream>>>(reg, rkcp, start, gmm, grad2, rec);
  k_accum  <<<NBSEG,     64,   0, stream>>>(rec, start, out);
}